// Round 1
// 285.688 us; speedup vs baseline: 1.0242x; 1.0242x over previous
//
#include <hip/hip_runtime.h>
#include <hip/hip_fp8.h>
#include <stdint.h>

// ---------------------------------------------------------------- constants
#define NB     8192     // batch
#define NF     256      // features
#define NHALF  128      // F/2
#define NHID   512      // hidden = 2F
#define NLAY   4        // coupling layers
#define NK     32768    // codebook size

#define SX     (1.0f / 16.0f)    // x scale for fp8 (|x|<=474/16=30 < 448)
#define SP     (256.0f)          // p scale for fp8 (Glorot +-0.0135*256=3.46)

typedef __attribute__((ext_vector_type(8))) short bf16x8;   // 8 bf16 = 4 VGPR
typedef __attribute__((ext_vector_type(4))) float f32x4;
typedef __attribute__((ext_vector_type(2))) long i64x2;     // 16 B = 2 fp8 frags

static __device__ __forceinline__ unsigned short f2bf(float f) {
  union { float f; unsigned int u; } v; v.f = f;
  return (unsigned short)((v.u + 0x7FFFu + ((v.u >> 16) & 1u)) >> 16);  // RNE
}
static __device__ __forceinline__ float bf2f(unsigned short u) {
  union { unsigned int u; float f; } v; v.u = ((unsigned int)u) << 16; return v.f;
}
static __device__ __forceinline__ unsigned char f2fp8(float f) {
  __hip_fp8_e4m3 q(f);                       // OCP e4m3fn, RNE + saturate
  return (unsigned char)q.__x;
}
static __device__ __forceinline__ float fp82f(unsigned char b) {
  __hip_fp8_e4m3 q; q.__x = b; return (float)q;
}
// permuted byte index inside a 256-k row: k' = q*64 + kc*8 + j for
// k = kc*32 + q*8 + j  -> one 16B load at q*64+kc2*16 = two K=32 fp8 frags
static __device__ __forceinline__ int kperm(int k) {
  return ((k >> 3) & 3) * 64 + ((k >> 5) << 3) + (k & 7);
}

// async global->LDS, 16B per lane; LDS dest = wave-uniform base + lane*16
static __device__ __forceinline__ void load_lds16(const void* g, void* l) {
  __builtin_amdgcn_global_load_lds(
      (const __attribute__((address_space(1))) unsigned int*)g,
      (__attribute__((address_space(3))) unsigned int*)l, 16, 0, 0);
}

// pack (score, idx) so u64 max == argmax with smallest-index tiebreak
static __device__ __forceinline__ unsigned long long packsi(float v, int idx) {
  unsigned int b = __float_as_uint(v);
  b = (b & 0x80000000u) ? ~b : (b | 0x80000000u);   // order-preserving map
  return ((unsigned long long)b << 32) | (unsigned int)(~(unsigned int)idx);
}

static __device__ __forceinline__ float fast_tanh(float x) {
  const float xc = fminf(fmaxf(x, -15.f), 15.f);
  const float e2 = __expf(2.f * xc);
  return 1.f - 2.f / (e2 + 1.f);
}

// LDS tile address: [kseg][row][64 shorts], 3-bit XOR chunk swizzle.
// Proven 0-conflict (R2/R4/R6) for ds_read_b128 with 16 lanes on rows.
static __device__ __forceinline__ int swadr(int kseg, int nrows, int row, int kin) {
  return (kseg * nrows + row) * 64 + (((kin >> 3) ^ (row & 7)) * 8) + (kin & 7);
}

// stage one 16 KB weight segment g (of 96) into dst: 4 global_load_lds x16B
// per thread. Per layer, 24 segs: nc8 0..7 x [W1(64 h-cols, K=128) | W2(K=32
// lo) | W2(K=32 hi)].  Each WAVE issues exactly 4 vmcnt events per call.
static __device__ __forceinline__ void stage_seg(
    int g, unsigned short* dst,
    const unsigned short* __restrict__ W1T,
    const unsigned short* __restrict__ W2I,
    int wave, int lane)
{
  const int l = g / 24, s = g % 24, nc = s / 3, t = s % 3;
  if (t == 0) {
    const unsigned short* W1l = W1T + (size_t)l * (NHID * NHALF) + (size_t)nc * 64 * 128;
#pragma unroll
    for (int u = 0; u < 4; u++) {
      const int chb = (u * 4 + wave) * 64;
      const int ch = chb + lane;
      const int kseg = ch >> 9, cs = ch & 511;
      const int row = cs >> 3, cc = (cs & 7) ^ (row & 7);
      load_lds16(W1l + (size_t)row * 128 + kseg * 64 + cc * 8, dst + chb * 8);
    }
  } else {
    const unsigned short* W2l = W2I + (size_t)l * (NF * NHID) + nc * 64 + (t - 1) * 32;
#pragma unroll
    for (int u = 0; u < 4; u++) {
      const int chb = (u * 4 + wave) * 64;
      const int ch = chb + lane;
      const int row = ch >> 2;
      const int cc = (ch & 3) ^ ((row >> 1) & 3);
      load_lds16(W2l + (size_t)row * NHID + cc * 8, dst + chb * 8);
    }
  }
}

// ---------------------------------------------------------------- fused flow (ALL 4 layers)
// One block = 16 rows, grid 512 (2 blocks/CU). DEEP-PIPELINED weight staging:
// 96 segments of 16 KB through a 3-buffer ring. Each iteration waits with a
// COUNTED s_waitcnt vmcnt(4) (DMA gs done, DMA gs+1 stays in flight across
// the barrier) instead of __syncthreads' vmcnt(0) drain -- the T3/T4 pattern.
// REQUIREMENT for the counted wait (in-order vmcnt retirement): no compiler-
// tracked global LOADS inside the loop -> all biases staged to LDS up front.
// Only loop vmcnt events: our 4 stage instrs (+ rare epilogue stores).
__global__ __launch_bounds__(256, 2)
void flow_all(const float* __restrict__ in,
              const unsigned short* __restrict__ W1T,   // [L][512][128]
              const unsigned short* __restrict__ W2I,   // [L][256][512] s/t interleaved
              const float* __restrict__ b1A,
              const float* __restrict__ bsA,
              const float* __restrict__ btA,
              float* __restrict__ xout,
              unsigned char* __restrict__ xf8,          // [NB][256] permuted fp8(x*SX)
              float* __restrict__ jac)
{
  __shared__ __align__(16) unsigned short Xb[2][16 * 128];   //  8 KB x-state
  __shared__ __align__(16) unsigned short Hs[16 * 64];       //  2 KB h chunk (64 cols)
  __shared__ __align__(16) unsigned short Bs[3][8192];       // 48 KB W ring (3x16KB)
  __shared__ float b1s[NLAY * NHID];                         //  8 KB bias
  __shared__ float bss[NLAY * NHALF];                        //  2 KB
  __shared__ float bts[NLAY * NHALF];                        //  2 KB
  __shared__ float jlds[3][16];
  const int tid = threadIdx.x;
  const int lane = tid & 63, wave = tid >> 6;
  const int q = lane >> 4, c = lane & 15;
  const int m0 = blockIdx.x * 16;

  // DMA(0) first: maximum latency cover (Bs disjoint from Xb/bias staging)
  stage_seg(0, Bs[0], W1T, W2I, wave, lane);

  // ---- init x-state: Xb[0]=bf16(in[:, :128]) (xa0), Xb[1]=bf16(in[:,128:]) (xb0)
#pragma unroll
  for (int v = 0; v < 4; v++) {
    const int t4 = tid + v * 256;            // 1024 float4s = 16 rows x 64
    const int row = t4 >> 6, f4 = t4 & 63;
    const float4 d = *(const float4*)(in + (size_t)(m0 + row) * NF + f4 * 4);
    unsigned short* dst = Xb[f4 >> 5];
    const int feat = (f4 & 31) * 4;
    const float vals[4] = {d.x, d.y, d.z, d.w};
#pragma unroll
    for (int u = 0; u < 4; u++) {
      const int fe = feat + u;
      dst[swadr(fe >> 6, 16, row, fe & 63)] = f2bf(vals[u]);
    }
  }

  // ---- biases -> LDS (keeps the main loop free of global loads; a global
  // load inside the loop would force an in-order vmcnt drain of the DMA ring)
#pragma unroll
  for (int v = 0; v < 8; v++) b1s[tid + v * 256] = b1A[tid + v * 256];
#pragma unroll
  for (int v = 0; v < 2; v++) {
    bss[tid + v * 256] = bsA[tid + v * 256];
    bts[tid + v * 256] = btA[tid + v * 256];
  }

  stage_seg(1, Bs[1], W1T, W2I, wave, lane);

  float jr[4] = {0.f, 0.f, 0.f, 0.f};
  bf16x8 af1[4];
  const f32x4 z = {0.f, 0.f, 0.f, 0.f};
  f32x4 acc2[4];

  for (int gs = 0; gs < 96; gs++) {
    // Counted wait: at most DMA(gs) [oldest 4] + DMA(gs+1) [newest 4] are in
    // flight -> vmcnt(4) proves DMA(gs) retired (in-order), DMA(gs+1) keeps
    // streaming across the barrier. lgkmcnt(0) covers Xb/Hs ds_writes.
    // Single asm: nothing (esp. ds_reads) can slip between wait and barrier.
    if (gs < 95)
      asm volatile("s_waitcnt vmcnt(4) lgkmcnt(0)\n\ts_barrier" ::: "memory");
    else
      asm volatile("s_waitcnt vmcnt(0) lgkmcnt(0)\n\ts_barrier" ::: "memory");

    // ring-safe prefetch: buffer (gs+2)%3 == (gs-1)%3 was last read in
    // compute(gs-1), which completed before the barrier above.
    if (gs + 2 < 96) stage_seg(gs + 2, Bs[(gs + 2) % 3], W1T, W2I, wave, lane);

    // ---- compute segment gs
    const int l = gs / 24, s = gs % 24, nc8 = s / 3, typ = s % 3;
    const unsigned short* B = Bs[gs % 3];
    unsigned short* XA = Xb[l & 1];
    unsigned short* XB = Xb[1 - (l & 1)];

    if (typ == 0) {                           // GEMM1 chunk: 64 h-cols, K=128
      if (s == 0) {                           // layer start: load A-frags, zero acc2
#pragma unroll
        for (int kw = 0; kw < 4; kw++) {
          const int kch = kw * 4 + q;
          af1[kw] = *(const bf16x8*)(XA + ((kch >> 3) * 16 + c) * 64 +
                                     (((kch & 7) ^ (c & 7)) * 8));
        }
#pragma unroll
        for (int j = 0; j < 4; j++) acc2[j] = z;
      }
      f32x4 acc1 = z;
      const int rb = wave * 16 + c;           // h-col within 64-chunk
#pragma unroll
      for (int kw = 0; kw < 4; kw++) {
        const int kseg = kw >> 1, g = (kw & 1) * 4 + q;
        const bf16x8 bf = *(const bf16x8*)(B + (kseg * 64 + rb) * 64 + ((g ^ (rb & 7)) * 8));
        acc1 = __builtin_amdgcn_mfma_f32_16x16x32_bf16(af1[kw], bf, acc1, 0, 0, 0);
      }
      const int hc = wave * 16 + c;
      const float bb = b1s[l * NHID + nc8 * 64 + hc];   // LDS, not global
#pragma unroll
      for (int r = 0; r < 4; r++) {
        float v = acc1[r] + bb;
        v = v > 0.f ? v : 0.f;
        Hs[swadr(0, 16, 4 * q + r, hc)] = f2bf(v);
      }
    } else {                                  // GEMM2: K=32 slice of this h chunk
      const int half = typ - 1;
      const bf16x8 afh = *(const bf16x8*)(Hs + c * 64 + (((half * 4 + q) ^ (c & 7)) * 8));
#pragma unroll
      for (int j = 0; j < 4; j++) {
        const int rb = wave * 64 + 16 * j + c;
        const bf16x8 bf = *(const bf16x8*)(B + rb * 32 + ((q ^ ((rb >> 1) & 3)) * 8));
        acc2[j] = __builtin_amdgcn_mfma_f32_16x16x32_bf16(afh, bf, acc2[j], 0, 0, 0);
      }
    }

    // ---- coupling epilogue at layer end (even col=s, odd col=t)
    if (s == 23) {
      const int parity = c & 1;
      const int lastl = (l == NLAY - 1);
      const float* bsl = bss + l * NHALF;     // LDS
      const float* btl = bts + l * NHALF;     // LDS
#pragma unroll
      for (int j = 0; j < 4; j++) {
        const int col = wave * 64 + 16 * j + c;
#pragma unroll
        for (int r = 0; r < 4; r++) {
          const float val = acc2[j][r];
          const float oth = __shfl_xor(val, 1);   // all lanes participate
          if (!parity) {
            const int feat = col >> 1;
            float sv = val + bsl[feat];
            if (!lastl) sv = fast_tanh(sv);
            const float t = oth + btl[feat];
            const int row = 4 * q + r;
            const int xaddr = swadr(feat >> 6, 16, row, feat & 63);
            const float xb = bf2f(XB[xaddr]);
            const float yb = xb * __expf(sv) + t;
            jr[r] += sv;
            XB[xaddr] = f2bf(yb);                 // in-place: same owner thread
            if (l >= 2) {
              const int k = lastl ? feat : (NHALF + feat);
              const size_t grow = (size_t)(m0 + row) * NF;
              xout[grow + k] = yb;
              xf8[(size_t)(m0 + row) * 256 + kperm(k)] = f2fp8(yb * SX);
            }
          }
        }
      }
    }
  }

  // jac: reduce 16 c-lanes in-wave, then cross-wave via LDS (sum, not overwrite)
  float v0[4];
#pragma unroll
  for (int r = 0; r < 4; r++) {
    float v = jr[r];
    v += __shfl_xor(v, 1); v += __shfl_xor(v, 2);
    v += __shfl_xor(v, 4); v += __shfl_xor(v, 8);
    if (c == 0) {
      if (wave) jlds[wave - 1][4 * q + r] = v;
      else v0[r] = v;
    }
  }
  __syncthreads();
  if (wave == 0 && c == 0) {
#pragma unroll
    for (int r = 0; r < 4; r++) {
      const int row = 4 * q + r;
      jac[m0 + row] = v0[r] + jlds[0][row] + jlds[1][row] + jlds[2][row];
    }
  }
}

// ---------------------------------------------------------------- VQ argmax (fp8)
// Grid 512: slice = bx & 15 (XCD-pinned, 1 MB P8 slice per XCD -> L2-resident),
// m-group = bx >> 4 (256 rows). 64 register-resident fp8 X rows per wave.
// P8 now DOUBLE-BUFFERED (2x16 KB): one barrier per tile; the next tile's DMA
// streams under the full ~5000-cycle MFMA window (compute >> DMA, so plain
// __syncthreads' drain at the NEXT barrier is exactly the wait we need).
// nbh loads hoisted BEFORE the DMA issue so the compiler's wait for them is
// vmcnt(4), not an in-order drain of the prefetch.
__global__ __launch_bounds__(256, 2)
void vq_argmax(const unsigned char* __restrict__ X8,   // [NB][256] permuted fp8
               const unsigned char* __restrict__ P8,   // [NK][256] permuted fp8
               const float* __restrict__ nbh,          // [NK] scaled 0.5||p||^2
               unsigned long long* __restrict__ gbest) // [NB] packed
{
  __shared__ __align__(16) unsigned char Bs[2][64 * 256];  // 2x16 KB
  const int tid = threadIdx.x;
  const int lane = tid & 63, wave = tid >> 6;
  const int y = blockIdx.x & 15;
  const int m0 = (blockIdx.x >> 4) * 256;
  const int q = lane >> 4, c = lane & 15;
  const int mw = m0 + wave * 64;

  long af[4][8];
#pragma unroll
  for (int i = 0; i < 4; i++) {
    const unsigned char* xr = X8 + (size_t)(mw + 16 * i + c) * 256 + q * 64;
#pragma unroll
    for (int kc2 = 0; kc2 < 4; kc2++) {
      const i64x2 v = *(const i64x2*)(xr + kc2 * 16);
      af[i][2 * kc2] = v.x; af[i][2 * kc2 + 1] = v.y;
    }
  }

  float bestv[16];
  int besti[16];
#pragma unroll
  for (int t = 0; t < 16; t++) { bestv[t] = -1e30f; besti[t] = 0; }

  // stage tile 0: slot (row,gslot) holds src chunk gslot^(row&15)
  {
    const int n0s = y * 2048;
#pragma unroll
    for (int u = 0; u < 4; u++) {
      const int chb = (u * 4 + wave) * 64;
      const int ch = chb + lane;
      const int row = ch >> 4, gslot = ch & 15;
      load_lds16(P8 + (size_t)(n0s + row) * 256 + (gslot ^ (row & 15)) * 16,
                 Bs[0] + chb * 16);
    }
  }

  for (int nt = 0; nt < 32; nt++) {
    const int n0 = y * 2048 + nt * 64;
    __syncthreads();     // DMA(nt) landed; prev reads of the other buffer done

    // hoist -0.5||p||^2 terms (issued BEFORE the next DMA -> no ring drain)
    float nbr[4];
#pragma unroll
    for (int j = 0; j < 4; j++) nbr[j] = nbh[n0 + 16 * j + c];

    if (nt + 1 < 32) {                        // prefetch tile nt+1
      const int n0s = n0 + 64;
      unsigned char* dst = Bs[(nt + 1) & 1];
#pragma unroll
      for (int u = 0; u < 4; u++) {
        const int chb = (u * 4 + wave) * 64;
        const int ch = chb + lane;
        const int row = ch >> 4, gslot = ch & 15;
        load_lds16(P8 + (size_t)(n0s + row) * 256 + (gslot ^ (row & 15)) * 16,
                   dst + chb * 16);
      }
    }

    const unsigned char* Bt = Bs[nt & 1];
    const f32x4 z = {0.f, 0.f, 0.f, 0.f};
    f32x4 acc[4][4];
#pragma unroll
    for (int i = 0; i < 4; i++)
#pragma unroll
      for (int j = 0; j < 4; j++) acc[i][j] = z;

#pragma unroll
    for (int kc2 = 0; kc2 < 4; kc2++) {
      const int g = q * 4 + kc2;
#pragma unroll
      for (int j = 0; j < 4; j++) {
        const int rb = 16 * j + c;
        const i64x2 b2 = *(const i64x2*)(Bt + rb * 256 + ((g ^ (rb & 15)) * 16));
#pragma unroll
        for (int i = 0; i < 4; i++) {
          acc[i][j] = __builtin_amdgcn_mfma_f32_16x16x32_fp8_fp8(af[i][2 * kc2],     b2.x, acc[i][j], 0, 0, 0);
          acc[i][j] = __builtin_amdgcn_mfma_f32_16x16x32_fp8_fp8(af[i][2 * kc2 + 1], b2.y, acc[i][j], 0, 0, 0);
        }
      }
    }

    // lane-local running argmax (ascending col + strict > = lowest-index ties)
#pragma unroll
    for (int j = 0; j < 4; j++) {
      const int col = n0 + 16 * j + c;
      const float nb = nbr[j];
#pragma unroll
      for (int i = 0; i < 4; i++)
#pragma unroll
        for (int r = 0; r < 4; r++) {
          const float sc = acc[i][j][r] - nb;
          const int t = i * 4 + r;
          if (sc > bestv[t]) { bestv[t] = sc; besti[t] = col; }
        }
    }
  }

  // reduce across 16 c-lanes per slot; rows unique per (wave, i, q, r)
#pragma unroll
  for (int t = 0; t < 16; t++) {
    float lv = bestv[t]; int li = besti[t];
#pragma unroll
    for (int mk = 8; mk >= 1; mk >>= 1) {
      const float ov = __shfl_xor(lv, mk);
      const int oi = __shfl_xor(li, mk);
      if (ov > lv || (ov == lv && oi < li)) { lv = ov; li = oi; }
    }
    if (c == 0) {
      const int row = mw + 16 * (t >> 2) + q * 4 + (t & 3);
      atomicMax(&gbest[row], packsi(lv, li));
    }
  }
}

// ---------------------------------------------------------------- fused prep
// bx [0,2048): prior -> permuted fp8 (scale SP) + scaled nbh | [2048,2112):
// W1 transpose | [2112,2240): Ws/Wt -> W2I interleave | [2240,2272): init
__global__ void prep_all(const float* __restrict__ W1,
                         const float* __restrict__ Ws,
                         const float* __restrict__ Wt,
                         const float* __restrict__ prior,
                         unsigned short* __restrict__ W1T,
                         unsigned short* __restrict__ W2I,
                         unsigned char* __restrict__ p8,
                         float* __restrict__ nbh,
                         unsigned long long* __restrict__ gbest,
                         float* __restrict__ accum)
{
  __shared__ float ts[64 * 65];
  const int bx = blockIdx.x;
  const int tid = threadIdx.x;
  if (bx < 2048) {
    const int k = bx * 16 + (tid >> 4);      // code index
    const int l16 = tid & 15;
    float s = 0.f;
#pragma unroll
    for (int v = 0; v < 4; v++) {
      const int off = (v * 16 + l16) * 4;    // k-offset, multiple of 4
      const float4 d = *(const float4*)(prior + (size_t)k * NF + off);
      uchar4 o;
      o.x = f2fp8(d.x * SP); o.y = f2fp8(d.y * SP);
      o.z = f2fp8(d.z * SP); o.w = f2fp8(d.w * SP);
      *(uchar4*)(p8 + (size_t)k * 256 + kperm(off)) = o;   // 4 consec bytes
      const float q0 = fp82f(o.x), q1 = fp82f(o.y), q2 = fp82f(o.z), q3 = fp82f(o.w);
      s += q0 * q0 + q1 * q1 + q2 * q2 + q3 * q3;
    }
#pragma unroll
    for (int mk = 8; mk >= 1; mk >>= 1) s += __shfl_xor(s, mk);
    if (l16 == 0) nbh[k] = 0.5f * s * (SX / SP);   // consistent scaled domain
  } else if (bx < 2112) {
    const int job = bx - 2048;
    const int l = job >> 4, t = job & 15;
    const int k0 = (t >> 3) * 64, n0 = (t & 7) * 64;
    const float* src = W1 + (size_t)l * NHALF * NHID;
#pragma unroll
    for (int v = 0; v < 16; v++) {
      const int e = tid + v * 256;
      const int kk = e >> 6, nn = e & 63;
      ts[kk * 65 + nn] = src[(size_t)(k0 + kk) * NHID + n0 + nn];
    }
    __syncthreads();
    unsigned short* dst = W1T + (size_t)l * NHID * NHALF;
#pragma unroll
    for (int v = 0; v < 16; v++) {
      const int e = tid + v * 256;
      const int nn = e >> 6, kk = e & 63;
      dst[(size_t)(n0 + nn) * NHALF + k0 + kk] = f2bf(ts[kk * 65 + nn]);
    }
  } else if (bx < 2240) {
    const int job = bx - 2112;
    const int l = job >> 5, rem = job & 31;
    const int b = rem >> 4;
    const int k0 = ((rem >> 1) & 7) * 64;
    const int f0 = (rem & 1) * 64;
    const float* src = (b ? Wt : Ws) + (size_t)l * NHID * NHALF;
#pragma unroll
    for (int v = 0; v < 16; v++) {
      const int e = tid + v * 256;
      const int kk = e >> 6, nn = e & 63;
      ts[kk * 65 + nn] = src[(size_t)(k0 + kk) * NHALF + f0 + nn];
    }
    __syncthreads();
#pragma unroll
    for (int v = 0; v < 16; v++) {
      const int e = tid + v * 256;
      const int nn = e >> 6, kk = e & 63;
      W2I[((size_t)l * NF + 2 * (f0 + nn) + b) * NHID + k0 + kk] = f2bf(ts[kk * 65 + nn]);
    }
  } else {
    const int idx = (bx - 2240) * 256 + tid;
    if (idx < NB) gbest[idx] = 0ull;
    if (idx < 4) accum[idx] = 0.f;    // [0]=dist [1]=jac [2]=ticket [3]=spare
  }
}

// ---------------------------------------------------------------- VQ finalize (+ fused loss)
// Last-arriving block (device-scope ticket on accum[2]) computes the scalar
// loss; accumulators read back via atomicAdd(p, 0) for cross-XCD coherence.
__global__ void vq_finalize(const float* __restrict__ X,      // d_out x, fp32
                            const float* __restrict__ prior,
                            const unsigned long long* __restrict__ gbest,
                            const float* __restrict__ jac,
                            float* __restrict__ accum,        // [0]=dist,[1]=jac,[2]=ticket
                            float* __restrict__ loss)
{
  const int wave = threadIdx.x >> 6, lane = threadIdx.x & 63;
  const int gw = blockIdx.x * 4 + wave;        // 1024 waves, 8 rows each
  float accd = 0.f, accj = 0.f;
  for (int r = 0; r < 8; r++) {
    const int row = gw * 8 + r;
    const unsigned int idx = ~(unsigned int)(gbest[row]);   // low 32 bits = ~idx
    const float* x = X + (size_t)row * NF;
    const float* p = prior + (size_t)idx * NF;
#pragma unroll
    for (int u = 0; u < 4; u++) {
      const int d = lane + u * 64;
      const float df = x[d] - p[d];
      accd += df * df;
    }
    if (lane == 0) accj += jac[row];
  }
#pragma unroll
  for (int mk = 32; mk >= 1; mk >>= 1) {
    accd += __shfl_xor(accd, mk);
    accj += __shfl_xor(accj, mk);
  }
  __shared__ float sd[4], sj[4];
  if (lane == 0) { sd[wave] = accd; sj[wave] = accj; }
  __syncthreads();
  if (threadIdx.x == 0) {
    atomicAdd(&accum[0], sd[0] + sd[1] + sd[2] + sd[3]);
    atomicAdd(&accum[1], sj[0] + sj[1] + sj[2] + sj[3]);
    __threadfence();                                        // release our adds
    const unsigned int t = atomicAdd((unsigned int*)&accum[2], 1u);
    if (t == 255u) {                                        // last of 256 blocks
      const float d = atomicAdd(&accum[0], 0.f);            // coherent read
      const float jv = atomicAdd(&accum[1], 0.f);
      loss[0] = 1.25f * (0.5f * d / (float)NB) - jv / (float)NB;
    }
  }
}

// ---------------------------------------------------------------- launch
extern "C" void kernel_launch(void* const* d_in, const int* in_sizes, int n_in,
                              void* d_out, int out_size, void* d_ws, size_t ws_size,
                              hipStream_t stream)
{
  (void)in_sizes; (void)n_in; (void)out_size; (void)ws_size;
  const float* inputs = (const float*)d_in[0];
  const float* W1 = (const float*)d_in[1];
  const float* b1 = (const float*)d_in[2];
  const float* Ws = (const float*)d_in[3];
  const float* bs = (const float*)d_in[4];
  const float* Wt = (const float*)d_in[5];
  const float* bt = (const float*)d_in[6];
  const float* prior = (const float*)d_in[7];

  char* p = (char*)d_ws;
  auto alloc = [&](size_t bytes) { char* r = p; p += (bytes + 255) & ~(size_t)255; return r; };
  unsigned short* W1T  = (unsigned short*)alloc((size_t)NLAY * NHID * NHALF * 2);
  unsigned short* W2I  = (unsigned short*)alloc((size_t)NLAY * NF * NHID * 2);
  unsigned char* P8    = (unsigned char*)alloc((size_t)NK * 256);
  float* NBH           = (float*)alloc((size_t)NK * 4);
  unsigned char* XF8   = (unsigned char*)alloc((size_t)NB * 256);
  float* JAC           = (float*)alloc((size_t)NB * 4);
  unsigned long long* GBEST = (unsigned long long*)alloc((size_t)NB * 8);
  float* ACC           = (float*)alloc(256);

  float* xout = (float*)d_out;                 // [NB][NF]
  float* loss = xout + (size_t)NB * NF;        // scalar

  prep_all<<<dim3(2272), 256, 0, stream>>>(
      W1, Ws, Wt, prior, W1T, W2I, P8, NBH, GBEST, ACC);

  flow_all<<<dim3(NB / 16), 256, 0, stream>>>(
      inputs, W1T, W2I, b1, bs, bt, xout, XF8, JAC);

  vq_argmax<<<dim3(32 * 16), 256, 0, stream>>>(XF8, P8, NBH, GBEST);
  vq_finalize<<<dim3(256), 256, 0, stream>>>(xout, prior, GBEST, JAC, ACC, loss);
}

// Round 2
// 259.445 us; speedup vs baseline: 1.1278x; 1.1012x over previous
//
#include <hip/hip_runtime.h>
#include <hip/hip_fp8.h>
#include <stdint.h>

// ---------------------------------------------------------------- constants
#define NB     8192     // batch
#define NF     256      // features
#define NHALF  128      // F/2
#define NHID   512      // hidden = 2F
#define NLAY   4        // coupling layers
#define NK     32768    // codebook size

#define SX     (1.0f / 16.0f)    // x scale for fp8 (|x|<=474/16=30 < 448)
#define SP     (256.0f)          // p scale for fp8 (Glorot +-0.0135*256=3.46)

typedef __attribute__((ext_vector_type(8))) short bf16x8;   // 8 bf16 = 4 VGPR
typedef __attribute__((ext_vector_type(4))) float f32x4;
typedef __attribute__((ext_vector_type(8))) int i32x8;      // 32 B MX fp8 frag

static __device__ __forceinline__ unsigned short f2bf(float f) {
  union { float f; unsigned int u; } v; v.f = f;
  return (unsigned short)((v.u + 0x7FFFu + ((v.u >> 16) & 1u)) >> 16);  // RNE
}
static __device__ __forceinline__ float bf2f(unsigned short u) {
  union { unsigned int u; float f; } v; v.u = ((unsigned int)u) << 16; return v.f;
}
static __device__ __forceinline__ unsigned char f2fp8(float f) {
  __hip_fp8_e4m3 q(f);                       // OCP e4m3fn, RNE + saturate
  return (unsigned char)q.__x;
}
static __device__ __forceinline__ float fp82f(unsigned char b) {
  __hip_fp8_e4m3 q; q.__x = b; return (float)q;
}

// async global->LDS, 16B per lane; LDS dest = wave-uniform base + lane*16
static __device__ __forceinline__ void load_lds16(const void* g, void* l) {
  __builtin_amdgcn_global_load_lds(
      (const __attribute__((address_space(1))) unsigned int*)g,
      (__attribute__((address_space(3))) unsigned int*)l, 16, 0, 0);
}

// pack (score, idx) so u64 max == argmax with smallest-index tiebreak
static __device__ __forceinline__ unsigned long long packsi(float v, int idx) {
  unsigned int b = __float_as_uint(v);
  b = (b & 0x80000000u) ? ~b : (b | 0x80000000u);   // order-preserving map
  return ((unsigned long long)b << 32) | (unsigned int)(~(unsigned int)idx);
}

static __device__ __forceinline__ float fast_tanh(float x) {
  const float xc = fminf(fmaxf(x, -15.f), 15.f);
  const float e2 = __expf(2.f * xc);
  return 1.f - 2.f / (e2 + 1.f);
}

// LDS tile address: [kseg][row][64 shorts], 3-bit XOR chunk swizzle.
// Proven 0-conflict (R2/R4/R6) for ds_read_b128 with 16 lanes on rows.
static __device__ __forceinline__ int swadr(int kseg, int nrows, int row, int kin) {
  return (kseg * nrows + row) * 64 + (((kin >> 3) ^ (row & 7)) * 8) + (kin & 7);
}

// stage one 16 KB weight segment g (of 96) into dst: 4 global_load_lds x16B
// per thread. Per layer, 24 segs: 8 chunk-groups x [W1(64 h-cols, K=128) |
// W2 slice A | W2 slice B].  PER-BLOCK DECORRELATION: chunk order rotated by
// bxr and the two GEMM2 k-halves swapped by hswap, so the 64 blocks per XCD
// split into 16 address-phase groups instead of all hitting the SAME 16 KB
// of L2 lines in lockstep (same-line serialization theory for the flow_all
// plateau). Legal: GEMM2 accumulates over chunks/halves in any order.
static __device__ __forceinline__ void stage_seg(
    int g, unsigned short* dst,
    const unsigned short* __restrict__ W1T,
    const unsigned short* __restrict__ W2I,
    int wave, int lane, int bxr, int hswap)
{
  const int l = g / 24, s = g % 24;
  const int nc = ((s / 3) + bxr) & 7;
  const int t = s % 3;
  if (t == 0) {
    const unsigned short* W1l = W1T + (size_t)l * (NHID * NHALF) + (size_t)nc * 64 * 128;
#pragma unroll
    for (int u = 0; u < 4; u++) {
      const int chb = (u * 4 + wave) * 64;
      const int ch = chb + lane;
      const int kseg = ch >> 9, cs = ch & 511;
      const int row = cs >> 3, cc = (cs & 7) ^ (row & 7);
      load_lds16(W1l + (size_t)row * 128 + kseg * 64 + cc * 8, dst + chb * 8);
    }
  } else {
    const int half = (t - 1) ^ hswap;
    const unsigned short* W2l = W2I + (size_t)l * (NF * NHID) + nc * 64 + half * 32;
#pragma unroll
    for (int u = 0; u < 4; u++) {
      const int chb = (u * 4 + wave) * 64;
      const int ch = chb + lane;
      const int row = ch >> 2;
      const int cc = (ch & 3) ^ ((row >> 1) & 3);
      load_lds16(W2l + (size_t)row * NHID + cc * 8, dst + chb * 8);
    }
  }
}

// ---------------------------------------------------------------- fused flow (ALL 4 layers)
// One block = 16 rows, grid 512 (2 blocks/CU). DEEP-PIPELINED weight staging:
// 96 segments of 16 KB through a 3-buffer ring, counted s_waitcnt vmcnt(4)
// (DMA gs done, DMA gs+1 stays in flight across the barrier). No compiler-
// tracked global LOADS inside the loop (biases staged to LDS up front) so
// the in-order vmcnt count stays exact.
__global__ __launch_bounds__(256, 2)
void flow_all(const float* __restrict__ in,
              const unsigned short* __restrict__ W1T,   // [L][512][128]
              const unsigned short* __restrict__ W2I,   // [L][256][512] s/t interleaved
              const float* __restrict__ b1A,
              const float* __restrict__ bsA,
              const float* __restrict__ btA,
              float* __restrict__ xout,
              unsigned char* __restrict__ xf8,          // [NB][256] fp8(x*SX), natural k
              float* __restrict__ jac)
{
  __shared__ __align__(16) unsigned short Xb[2][16 * 128];   //  8 KB x-state
  __shared__ __align__(16) unsigned short Hs[16 * 64];       //  2 KB h chunk (64 cols)
  __shared__ __align__(16) unsigned short Bs[3][8192];       // 48 KB W ring (3x16KB)
  __shared__ float b1s[NLAY * NHID];                         //  8 KB bias
  __shared__ float bss[NLAY * NHALF];                        //  2 KB
  __shared__ float bts[NLAY * NHALF];                        //  2 KB
  __shared__ float jlds[3][16];
  const int tid = threadIdx.x;
  const int lane = tid & 63, wave = tid >> 6;
  const int q = lane >> 4, c = lane & 15;
  const int m0 = blockIdx.x * 16;
  const int bxr = blockIdx.x & 7;
  const int hswap = (blockIdx.x >> 3) & 1;

  // DMA(0) first: maximum latency cover (Bs disjoint from Xb/bias staging)
  stage_seg(0, Bs[0], W1T, W2I, wave, lane, bxr, hswap);

  // ---- init x-state: Xb[0]=bf16(in[:, :128]) (xa0), Xb[1]=bf16(in[:,128:]) (xb0)
#pragma unroll
  for (int v = 0; v < 4; v++) {
    const int t4 = tid + v * 256;            // 1024 float4s = 16 rows x 64
    const int row = t4 >> 6, f4 = t4 & 63;
    const float4 d = *(const float4*)(in + (size_t)(m0 + row) * NF + f4 * 4);
    unsigned short* dst = Xb[f4 >> 5];
    const int feat = (f4 & 31) * 4;
    const float vals[4] = {d.x, d.y, d.z, d.w};
#pragma unroll
    for (int u = 0; u < 4; u++) {
      const int fe = feat + u;
      dst[swadr(fe >> 6, 16, row, fe & 63)] = f2bf(vals[u]);
    }
  }

  // ---- biases -> LDS (keeps the main loop free of global loads; a global
  // load inside the loop would force an in-order vmcnt drain of the DMA ring)
#pragma unroll
  for (int v = 0; v < 8; v++) b1s[tid + v * 256] = b1A[tid + v * 256];
#pragma unroll
  for (int v = 0; v < 2; v++) {
    bss[tid + v * 256] = bsA[tid + v * 256];
    bts[tid + v * 256] = btA[tid + v * 256];
  }

  stage_seg(1, Bs[1], W1T, W2I, wave, lane, bxr, hswap);

  float jr[4] = {0.f, 0.f, 0.f, 0.f};
  bf16x8 af1[4];
  const f32x4 z = {0.f, 0.f, 0.f, 0.f};
  f32x4 acc2[4];

  for (int gs = 0; gs < 96; gs++) {
    // Counted wait: at most DMA(gs) [oldest 4] + DMA(gs+1) [newest 4] are in
    // flight -> vmcnt(4) proves DMA(gs) retired (in-order), DMA(gs+1) keeps
    // streaming across the barrier. lgkmcnt(0) covers Xb/Hs ds_writes.
    // Single asm: nothing (esp. ds_reads) can slip between wait and barrier.
    if (gs < 95)
      asm volatile("s_waitcnt vmcnt(4) lgkmcnt(0)\n\ts_barrier" ::: "memory");
    else
      asm volatile("s_waitcnt vmcnt(0) lgkmcnt(0)\n\ts_barrier" ::: "memory");

    // ring-safe prefetch: buffer (gs+2)%3 == (gs-1)%3 was last read in
    // compute(gs-1), which completed before the barrier above.
    if (gs + 2 < 96) stage_seg(gs + 2, Bs[(gs + 2) % 3], W1T, W2I, wave, lane, bxr, hswap);

    // ---- compute segment gs
    const int l = gs / 24, s = gs % 24, typ = s % 3;
    const int nc8 = ((s / 3) + bxr) & 7;      // rotated chunk (bias index only)
    const unsigned short* B = Bs[gs % 3];
    unsigned short* XA = Xb[l & 1];
    unsigned short* XB = Xb[1 - (l & 1)];

    if (typ == 0) {                           // GEMM1 chunk: 64 h-cols, K=128
      if (s == 0) {                           // layer start: load A-frags, zero acc2
#pragma unroll
        for (int kw = 0; kw < 4; kw++) {
          const int kch = kw * 4 + q;
          af1[kw] = *(const bf16x8*)(XA + ((kch >> 3) * 16 + c) * 64 +
                                     (((kch & 7) ^ (c & 7)) * 8));
        }
#pragma unroll
        for (int j = 0; j < 4; j++) acc2[j] = z;
      }
      f32x4 acc1 = z;
      const int rb = wave * 16 + c;           // h-col within 64-chunk
#pragma unroll
      for (int kw = 0; kw < 4; kw++) {
        const int kseg = kw >> 1, g = (kw & 1) * 4 + q;
        const bf16x8 bf = *(const bf16x8*)(B + (kseg * 64 + rb) * 64 + ((g ^ (rb & 7)) * 8));
        acc1 = __builtin_amdgcn_mfma_f32_16x16x32_bf16(af1[kw], bf, acc1, 0, 0, 0);
      }
      const int hc = wave * 16 + c;
      const float bb = b1s[l * NHID + nc8 * 64 + hc];   // LDS, not global
#pragma unroll
      for (int r = 0; r < 4; r++) {
        float v = acc1[r] + bb;
        v = v > 0.f ? v : 0.f;
        Hs[swadr(0, 16, 4 * q + r, hc)] = f2bf(v);
      }
    } else {                                  // GEMM2: K=32 slice of this h chunk
      const int half = (typ - 1) ^ hswap;     // matches staged slice
      const bf16x8 afh = *(const bf16x8*)(Hs + c * 64 + (((half * 4 + q) ^ (c & 7)) * 8));
#pragma unroll
      for (int j = 0; j < 4; j++) {
        const int rb = wave * 64 + 16 * j + c;
        const bf16x8 bf = *(const bf16x8*)(B + rb * 32 + ((q ^ ((rb >> 1) & 3)) * 8));
        acc2[j] = __builtin_amdgcn_mfma_f32_16x16x32_bf16(afh, bf, acc2[j], 0, 0, 0);
      }
    }

    // ---- coupling epilogue at layer end (even col=s, odd col=t)
    if (s == 23) {
      const int parity = c & 1;
      const int lastl = (l == NLAY - 1);
      const float* bsl = bss + l * NHALF;     // LDS
      const float* btl = bts + l * NHALF;     // LDS
#pragma unroll
      for (int j = 0; j < 4; j++) {
        const int col = wave * 64 + 16 * j + c;
#pragma unroll
        for (int r = 0; r < 4; r++) {
          const float val = acc2[j][r];
          const float oth = __shfl_xor(val, 1);   // all lanes participate
          if (!parity) {
            const int feat = col >> 1;
            float sv = val + bsl[feat];
            if (!lastl) sv = fast_tanh(sv);
            const float t = oth + btl[feat];
            const int row = 4 * q + r;
            const int xaddr = swadr(feat >> 6, 16, row, feat & 63);
            const float xb = bf2f(XB[xaddr]);
            const float yb = xb * __expf(sv) + t;
            jr[r] += sv;
            XB[xaddr] = f2bf(yb);                 // in-place: same owner thread
            if (l >= 2) {
              const int k = lastl ? feat : (NHALF + feat);
              const size_t grow = (size_t)(m0 + row) * NF;
              xout[grow + k] = yb;
              xf8[(size_t)(m0 + row) * 256 + k] = f2fp8(yb * SX);  // natural order
            }
          }
        }
      }
    }
  }

  // jac: reduce 16 c-lanes in-wave, then cross-wave via LDS (sum, not overwrite)
  float v0[4];
#pragma unroll
  for (int r = 0; r < 4; r++) {
    float v = jr[r];
    v += __shfl_xor(v, 1); v += __shfl_xor(v, 2);
    v += __shfl_xor(v, 4); v += __shfl_xor(v, 8);
    if (c == 0) {
      if (wave) jlds[wave - 1][4 * q + r] = v;
      else v0[r] = v;
    }
  }
  __syncthreads();
  if (wave == 0 && c == 0) {
#pragma unroll
    for (int r = 0; r < 4; r++) {
      const int row = 4 * q + r;
      jac[m0 + row] = v0[r] + jlds[0][row] + jlds[1][row] + jlds[2][row];
    }
  }
}

// ---------------------------------------------------------------- VQ argmax (MX fp8)
// Grid 512: slice = bx & 15 (XCD-pinned), m-group = bx >> 4 (256 rows).
// NOW mfma_scale_f32_16x16x128_f8f6f4 with unit e8m0 scales (0x7F = 2^0):
// the only large-K fp8 MFMA, ~2.3x the 16x16x32 fp8 rate -> MFMA-pipe floor
// ~29 us. K=128 fragments = 32 CONTIGUOUS k-bytes per lane, so X8/P8 are in
// NATURAL k order (kperm gone). Correct under any internal k-permutation:
// A and B lane layouts are mirrored, so a shared permutation of k leaves the
// dot product invariant. -0.5||p||^2 is folded into the accumulator init
// (C-in = -nb), deleting 64 VALU subs/thread/tile from the argmax scan.
__global__ __launch_bounds__(256, 2)
void vq_argmax(const unsigned char* __restrict__ X8,   // [NB][256] fp8, natural k
               const unsigned char* __restrict__ P8,   // [NK][256] fp8, natural k
               const float* __restrict__ nbh,          // [NK] scaled 0.5||p||^2
               unsigned long long* __restrict__ gbest) // [NB] packed
{
  __shared__ __align__(16) unsigned char Bs[2][64 * 256];  // 2x16 KB
  const int tid = threadIdx.x;
  const int lane = tid & 63, wave = tid >> 6;
  const int y = blockIdx.x & 15;
  const int m0 = (blockIdx.x >> 4) * 256;
  const int q = lane >> 4, c = lane & 15;
  const int mw = m0 + wave * 64;
  const int one = 0x7F7F7F7F;                // e8m0 scale 1.0 in every byte

  // A-frags: 64 rows/wave x 256 k-bytes; lane (q,c): row 16i+c, half h,
  // bytes [h*128 + q*32, +32) -> i32x8
  i32x8 af[4][2];
#pragma unroll
  for (int i = 0; i < 4; i++) {
    const unsigned char* xr = X8 + (size_t)(mw + 16 * i + c) * 256 + q * 32;
#pragma unroll
    for (int h = 0; h < 2; h++) {
      const int4 lo = *(const int4*)(xr + h * 128);
      const int4 hi = *(const int4*)(xr + h * 128 + 16);
      af[i][h] = (i32x8){lo.x, lo.y, lo.z, lo.w, hi.x, hi.y, hi.z, hi.w};
    }
  }

  float bestv[16];
  int besti[16];
#pragma unroll
  for (int t = 0; t < 16; t++) { bestv[t] = -1e30f; besti[t] = 0; }

  // stage tile 0: slot (row,gslot) holds src chunk gslot^(row&15)
  {
    const int n0s = y * 2048;
#pragma unroll
    for (int u = 0; u < 4; u++) {
      const int chb = (u * 4 + wave) * 64;
      const int ch = chb + lane;
      const int row = ch >> 4, gslot = ch & 15;
      load_lds16(P8 + (size_t)(n0s + row) * 256 + (gslot ^ (row & 15)) * 16,
                 Bs[0] + chb * 16);
    }
  }

  for (int nt = 0; nt < 32; nt++) {
    const int n0 = y * 2048 + nt * 64;
    __syncthreads();     // DMA(nt) landed; prev reads of the other buffer done

    // hoist -0.5||p||^2 terms (issued BEFORE the next DMA -> no ring drain)
    float nbr[4];
#pragma unroll
    for (int j = 0; j < 4; j++) nbr[j] = nbh[n0 + 16 * j + c];

    if (nt + 1 < 32) {                        // prefetch tile nt+1
      const int n0s = n0 + 64;
      unsigned char* dst = Bs[(nt + 1) & 1];
#pragma unroll
      for (int u = 0; u < 4; u++) {
        const int chb = (u * 4 + wave) * 64;
        const int ch = chb + lane;
        const int row = ch >> 4, gslot = ch & 15;
        load_lds16(P8 + (size_t)(n0s + row) * 256 + (gslot ^ (row & 15)) * 16,
                   dst + chb * 16);
      }
    }

    const unsigned char* Bt = Bs[nt & 1];
    f32x4 acc[4][4];
#pragma unroll
    for (int i = 0; i < 4; i++)
#pragma unroll
      for (int j = 0; j < 4; j++)
        acc[i][j] = (f32x4){-nbr[j], -nbr[j], -nbr[j], -nbr[j]};

#pragma unroll
    for (int j = 0; j < 4; j++) {
      const unsigned char* base = Bt + (16 * j + c) * 256;
#pragma unroll
      for (int h = 0; h < 2; h++) {
        // B-frag: code row 16j+c, k-bytes [h*128 + q*32, +32), chunk-XOR swz
        const int4 b0 = *(const int4*)(base + ((8 * h + 2 * q)     ^ c) * 16);
        const int4 b1 = *(const int4*)(base + ((8 * h + 2 * q + 1) ^ c) * 16);
        const i32x8 bf = (i32x8){b0.x, b0.y, b0.z, b0.w, b1.x, b1.y, b1.z, b1.w};
#pragma unroll
        for (int i = 0; i < 4; i++)
          acc[i][j] = __builtin_amdgcn_mfma_scale_f32_16x16x128_f8f6f4(
              af[i][h], bf, acc[i][j], 0, 0, 0, one, 0, one);
      }
    }

    // lane-local running argmax; sc already includes -nb via C-init
#pragma unroll
    for (int j = 0; j < 4; j++) {
      const int col = n0 + 16 * j + c;
#pragma unroll
      for (int i = 0; i < 4; i++)
#pragma unroll
        for (int r = 0; r < 4; r++) {
          const float sc = acc[i][j][r];
          const int t = i * 4 + r;
          if (sc > bestv[t]) { bestv[t] = sc; besti[t] = col; }
        }
    }
  }

  // reduce across 16 c-lanes per slot; rows unique per (wave, i, q, r)
#pragma unroll
  for (int t = 0; t < 16; t++) {
    float lv = bestv[t]; int li = besti[t];
#pragma unroll
    for (int mk = 8; mk >= 1; mk >>= 1) {
      const float ov = __shfl_xor(lv, mk);
      const int oi = __shfl_xor(li, mk);
      if (ov > lv || (ov == lv && oi < li)) { lv = ov; li = oi; }
    }
    if (c == 0) {
      const int row = mw + 16 * (t >> 2) + q * 4 + (t & 3);
      atomicMax(&gbest[row], packsi(lv, li));
    }
  }
}

// ---------------------------------------------------------------- fused prep
// bx [0,2048): prior -> fp8 (scale SP, natural k order) + scaled nbh |
// [2048,2112): W1 transpose | [2112,2240): Ws/Wt -> W2I | [2240,2272): init
__global__ void prep_all(const float* __restrict__ W1,
                         const float* __restrict__ Ws,
                         const float* __restrict__ Wt,
                         const float* __restrict__ prior,
                         unsigned short* __restrict__ W1T,
                         unsigned short* __restrict__ W2I,
                         unsigned char* __restrict__ p8,
                         float* __restrict__ nbh,
                         unsigned long long* __restrict__ gbest,
                         float* __restrict__ accum)
{
  __shared__ float ts[64 * 65];
  const int bx = blockIdx.x;
  const int tid = threadIdx.x;
  if (bx < 2048) {
    const int k = bx * 16 + (tid >> 4);      // code index
    const int l16 = tid & 15;
    float s = 0.f;
#pragma unroll
    for (int v = 0; v < 4; v++) {
      const int off = (v * 16 + l16) * 4;    // k-offset, multiple of 4
      const float4 d = *(const float4*)(prior + (size_t)k * NF + off);
      uchar4 o;
      o.x = f2fp8(d.x * SP); o.y = f2fp8(d.y * SP);
      o.z = f2fp8(d.z * SP); o.w = f2fp8(d.w * SP);
      *(uchar4*)(p8 + (size_t)k * 256 + off) = o;          // natural order
      const float q0 = fp82f(o.x), q1 = fp82f(o.y), q2 = fp82f(o.z), q3 = fp82f(o.w);
      s += q0 * q0 + q1 * q1 + q2 * q2 + q3 * q3;
    }
#pragma unroll
    for (int mk = 8; mk >= 1; mk >>= 1) s += __shfl_xor(s, mk);
    if (l16 == 0) nbh[k] = 0.5f * s * (SX / SP);   // consistent scaled domain
  } else if (bx < 2112) {
    const int job = bx - 2048;
    const int l = job >> 4, t = job & 15;
    const int k0 = (t >> 3) * 64, n0 = (t & 7) * 64;
    const float* src = W1 + (size_t)l * NHALF * NHID;
#pragma unroll
    for (int v = 0; v < 16; v++) {
      const int e = tid + v * 256;
      const int kk = e >> 6, nn = e & 63;
      ts[kk * 65 + nn] = src[(size_t)(k0 + kk) * NHID + n0 + nn];
    }
    __syncthreads();
    unsigned short* dst = W1T + (size_t)l * NHID * NHALF;
#pragma unroll
    for (int v = 0; v < 16; v++) {
      const int e = tid + v * 256;
      const int nn = e >> 6, kk = e & 63;
      dst[(size_t)(n0 + nn) * NHALF + k0 + kk] = f2bf(ts[kk * 65 + nn]);
    }
  } else if (bx < 2240) {
    const int job = bx - 2112;
    const int l = job >> 5, rem = job & 31;
    const int b = rem >> 4;
    const int k0 = ((rem >> 1) & 7) * 64;
    const int f0 = (rem & 1) * 64;
    const float* src = (b ? Wt : Ws) + (size_t)l * NHID * NHALF;
#pragma unroll
    for (int v = 0; v < 16; v++) {
      const int e = tid + v * 256;
      const int kk = e >> 6, nn = e & 63;
      ts[kk * 65 + nn] = src[(size_t)(k0 + kk) * NHALF + f0 + nn];
    }
    __syncthreads();
#pragma unroll
    for (int v = 0; v < 16; v++) {
      const int e = tid + v * 256;
      const int nn = e >> 6, kk = e & 63;
      W2I[((size_t)l * NF + 2 * (f0 + nn) + b) * NHID + k0 + kk] = f2bf(ts[kk * 65 + nn]);
    }
  } else {
    const int idx = (bx - 2240) * 256 + tid;
    if (idx < NB) gbest[idx] = 0ull;
    if (idx < 4) accum[idx] = 0.f;    // [0]=dist [1]=jac [2]=ticket [3]=spare
  }
}

// ---------------------------------------------------------------- VQ finalize (+ fused loss)
// Last-arriving block (device-scope ticket on accum[2]) computes the scalar
// loss; accumulators read back via atomicAdd(p, 0) for cross-XCD coherence.
__global__ void vq_finalize(const float* __restrict__ X,      // d_out x, fp32
                            const float* __restrict__ prior,
                            const unsigned long long* __restrict__ gbest,
                            const float* __restrict__ jac,
                            float* __restrict__ accum,        // [0]=dist,[1]=jac,[2]=ticket
                            float* __restrict__ loss)
{
  const int wave = threadIdx.x >> 6, lane = threadIdx.x & 63;
  const int gw = blockIdx.x * 4 + wave;        // 1024 waves, 8 rows each
  float accd = 0.f, accj = 0.f;
  for (int r = 0; r < 8; r++) {
    const int row = gw * 8 + r;
    const unsigned int idx = ~(unsigned int)(gbest[row]);   // low 32 bits = ~idx
    const float* x = X + (size_t)row * NF;
    const float* p = prior + (size_t)idx * NF;
#pragma unroll
    for (int u = 0; u < 4; u++) {
      const int d = lane + u * 64;
      const float df = x[d] - p[d];
      accd += df * df;
    }
    if (lane == 0) accj += jac[row];
  }
#pragma unroll
  for (int mk = 32; mk >= 1; mk >>= 1) {
    accd += __shfl_xor(accd, mk);
    accj += __shfl_xor(accj, mk);
  }
  __shared__ float sd[4], sj[4];
  if (lane == 0) { sd[wave] = accd; sj[wave] = accj; }
  __syncthreads();
  if (threadIdx.x == 0) {
    atomicAdd(&accum[0], sd[0] + sd[1] + sd[2] + sd[3]);
    atomicAdd(&accum[1], sj[0] + sj[1] + sj[2] + sj[3]);
    __threadfence();                                        // release our adds
    const unsigned int t = atomicAdd((unsigned int*)&accum[2], 1u);
    if (t == 255u) {                                        // last of 256 blocks
      const float d = atomicAdd(&accum[0], 0.f);            // coherent read
      const float jv = atomicAdd(&accum[1], 0.f);
      loss[0] = 1.25f * (0.5f * d / (float)NB) - jv / (float)NB;
    }
  }
}

// ---------------------------------------------------------------- launch
extern "C" void kernel_launch(void* const* d_in, const int* in_sizes, int n_in,
                              void* d_out, int out_size, void* d_ws, size_t ws_size,
                              hipStream_t stream)
{
  (void)in_sizes; (void)n_in; (void)out_size; (void)ws_size;
  const float* inputs = (const float*)d_in[0];
  const float* W1 = (const float*)d_in[1];
  const float* b1 = (const float*)d_in[2];
  const float* Ws = (const float*)d_in[3];
  const float* bs = (const float*)d_in[4];
  const float* Wt = (const float*)d_in[5];
  const float* bt = (const float*)d_in[6];
  const float* prior = (const float*)d_in[7];

  char* p = (char*)d_ws;
  auto alloc = [&](size_t bytes) { char* r = p; p += (bytes + 255) & ~(size_t)255; return r; };
  unsigned short* W1T  = (unsigned short*)alloc((size_t)NLAY * NHID * NHALF * 2);
  unsigned short* W2I  = (unsigned short*)alloc((size_t)NLAY * NF * NHID * 2);
  unsigned char* P8    = (unsigned char*)alloc((size_t)NK * 256);
  float* NBH           = (float*)alloc((size_t)NK * 4);
  unsigned char* XF8   = (unsigned char*)alloc((size_t)NB * 256);
  float* JAC           = (float*)alloc((size_t)NB * 4);
  unsigned long long* GBEST = (unsigned long long*)alloc((size_t)NB * 8);
  float* ACC           = (float*)alloc(256);

  float* xout = (float*)d_out;                 // [NB][NF]
  float* loss = xout + (size_t)NB * NF;        // scalar

  prep_all<<<dim3(2272), 256, 0, stream>>>(
      W1, Ws, Wt, prior, W1T, W2I, P8, NBH, GBEST, ACC);

  flow_all<<<dim3(NB / 16), 256, 0, stream>>>(
      inputs, W1T, W2I, b1, bs, bt, xout, XF8, JAC);

  vq_argmax<<<dim3(32 * 16), 256, 0, stream>>>(XF8, P8, NBH, GBEST);
  vq_finalize<<<dim3(256), 256, 0, stream>>>(xout, prior, GBEST, JAC, ACC, loss);
}

// Round 3
// 257.026 us; speedup vs baseline: 1.1384x; 1.0094x over previous
//
#include <hip/hip_runtime.h>
#include <hip/hip_fp8.h>
#include <stdint.h>

// ---------------------------------------------------------------- constants
#define NB     8192     // batch
#define NF     256      // features
#define NHALF  128      // F/2
#define NHID   512      // hidden = 2F
#define NLAY   4        // coupling layers
#define NK     32768    // codebook size

#define SX     (1.0f / 16.0f)    // x scale for fp8 (|x|<=474/16=30 < 448)
#define SP     (256.0f)          // p scale for fp8 (Glorot +-0.0135*256=3.46)

typedef __attribute__((ext_vector_type(8))) short bf16x8;   // 8 bf16 = 4 VGPR
typedef __attribute__((ext_vector_type(4))) float f32x4;
typedef __attribute__((ext_vector_type(8))) int i32x8;      // 32 B MX fp8 frag

static __device__ __forceinline__ unsigned short f2bf(float f) {
  union { float f; unsigned int u; } v; v.f = f;
  return (unsigned short)((v.u + 0x7FFFu + ((v.u >> 16) & 1u)) >> 16);  // RNE
}
static __device__ __forceinline__ float bf2f(unsigned short u) {
  union { unsigned int u; float f; } v; v.u = ((unsigned int)u) << 16; return v.f;
}
static __device__ __forceinline__ unsigned char f2fp8(float f) {
  __hip_fp8_e4m3 q(f);                       // OCP e4m3fn, RNE + saturate
  return (unsigned char)q.__x;
}
static __device__ __forceinline__ float fp82f(unsigned char b) {
  __hip_fp8_e4m3 q; q.__x = b; return (float)q;
}

// async global->LDS, 16B per lane; LDS dest = wave-uniform base + lane*16
static __device__ __forceinline__ void load_lds16(const void* g, void* l) {
  __builtin_amdgcn_global_load_lds(
      (const __attribute__((address_space(1))) unsigned int*)g,
      (__attribute__((address_space(3))) unsigned int*)l, 16, 0, 0);
}

// pack (score, idx) so u64 max == argmax with smallest-index tiebreak
static __device__ __forceinline__ unsigned long long packsi(float v, int idx) {
  unsigned int b = __float_as_uint(v);
  b = (b & 0x80000000u) ? ~b : (b | 0x80000000u);   // order-preserving map
  return ((unsigned long long)b << 32) | (unsigned int)(~(unsigned int)idx);
}

static __device__ __forceinline__ float fast_tanh(float x) {
  const float xc = fminf(fmaxf(x, -15.f), 15.f);
  const float e2 = __expf(2.f * xc);
  return 1.f - 2.f / (e2 + 1.f);
}

// LDS tile address: [kseg][row][64 shorts], 3-bit XOR chunk swizzle.
// Proven 0-conflict (R2/R4/R6) for ds_read_b128 with 16 lanes on rows.
static __device__ __forceinline__ int swadr(int kseg, int nrows, int row, int kin) {
  return (kseg * nrows + row) * 64 + (((kin >> 3) ^ (row & 7)) * 8) + (kin & 7);
}

// stage one 16 KB weight segment g (of 96) into dst: 512 threads x 2 rounds
// x 16B. Per layer, 24 segs: 8 chunk-groups x [W1(64 h-cols, K=128) | W2
// slice A | W2 slice B].  PER-BLOCK DECORRELATION: chunk order rotated by
// bxr, GEMM2 k-halves swapped by hswap (16 address-phase groups per XCD).
// Legal: GEMM2 accumulates over chunks/halves in any order.
// Each WAVE issues exactly 2 vmcnt events per call.
static __device__ __forceinline__ void stage_seg(
    int g, unsigned short* dst,
    const unsigned short* __restrict__ W1T,
    const unsigned short* __restrict__ W2I,
    int wave, int lane, int bxr, int hswap)
{
  const int l = g / 24, s = g % 24;
  const int nc = ((s / 3) + bxr) & 7;
  const int t = s % 3;
  if (t == 0) {
    const unsigned short* W1l = W1T + (size_t)l * (NHID * NHALF) + (size_t)nc * 64 * 128;
#pragma unroll
    for (int u = 0; u < 2; u++) {
      const int chb = (u * 8 + wave) * 64;
      const int ch = chb + lane;
      const int kseg = ch >> 9, cs = ch & 511;
      const int row = cs >> 3, cc = (cs & 7) ^ (row & 7);
      load_lds16(W1l + (size_t)row * 128 + kseg * 64 + cc * 8, dst + chb * 8);
    }
  } else {
    const int half = (t - 1) ^ hswap;
    const unsigned short* W2l = W2I + (size_t)l * (NF * NHID) + nc * 64 + half * 32;
#pragma unroll
    for (int u = 0; u < 2; u++) {
      const int chb = (u * 8 + wave) * 64;
      const int ch = chb + lane;
      const int row = ch >> 2;
      const int cc = (ch & 3) ^ ((row >> 1) & 3);
      load_lds16(W2l + (size_t)row * NHID + cc * 8, dst + chb * 8);
    }
  }
}

// ---------------------------------------------------------------- fused flow (ALL 4 layers)
// ONE 512-thread block per CU (grid 256, 32 rows/block): halves per-XCD L2
// weight traffic vs 2x256, and frees LDS for a FIVE-deep staging ring (80 KB)
// -> DMA(g) issued at iter g-4, ~3 iterations of latency cover, counted
// s_waitcnt vmcnt(6) at the barrier (3 segs x 2 DMA-instr/wave in flight).
// 8 waves: wave (rg=w>>2, cg=w&3) owns rows rg*16..+16 and col-group cg.
// No compiler-tracked global LOADS in the loop (biases staged to LDS) so the
// in-order vmcnt count stays exact.
__global__ __launch_bounds__(512, 2)
void flow_all(const float* __restrict__ in,
              const unsigned short* __restrict__ W1T,   // [L][512][128]
              const unsigned short* __restrict__ W2I,   // [L][256][512] s/t interleaved
              const float* __restrict__ b1A,
              const float* __restrict__ bsA,
              const float* __restrict__ btA,
              float* __restrict__ xout,
              unsigned char* __restrict__ xf8,          // [NB][256] fp8(x*SX), natural k
              float* __restrict__ jac)
{
  __shared__ __align__(16) unsigned short Xb[2][32 * 128];   // 16 KB x-state
  __shared__ __align__(16) unsigned short Hs[32 * 64];       //  4 KB h chunk (64 cols)
  __shared__ __align__(16) unsigned short Bs[5][8192];       // 80 KB W ring (5x16KB)
  __shared__ float b1s[NLAY * NHID];                         //  8 KB bias
  __shared__ float bss[NLAY * NHALF];                        //  2 KB
  __shared__ float bts[NLAY * NHALF];                        //  2 KB
  __shared__ float jlds[4][32];
  const int tid = threadIdx.x;
  const int lane = tid & 63, wave = tid >> 6;
  const int rg = wave >> 2, cg = wave & 3;
  const int q = lane >> 4, c = lane & 15;
  const int m0 = blockIdx.x * 32;
  const int bxr = blockIdx.x & 7;
  const int hswap = (blockIdx.x >> 3) & 1;

  // DMA(0) first: maximum latency cover (Bs disjoint from Xb/bias staging)
  stage_seg(0, Bs[0], W1T, W2I, wave, lane, bxr, hswap);

  // ---- init x-state: Xb[0]=bf16(in[:, :128]) (xa0), Xb[1]=bf16(in[:,128:])
#pragma unroll
  for (int v = 0; v < 4; v++) {
    const int t4 = tid + v * 512;            // 2048 float4s = 32 rows x 64
    const int row = t4 >> 6, f4 = t4 & 63;
    const float4 d = *(const float4*)(in + (size_t)(m0 + row) * NF + f4 * 4);
    unsigned short* dst = Xb[f4 >> 5];
    const int feat = (f4 & 31) * 4;
    const float vals[4] = {d.x, d.y, d.z, d.w};
#pragma unroll
    for (int u = 0; u < 4; u++) {
      const int fe = feat + u;
      dst[swadr(fe >> 6, 32, row, fe & 63)] = f2bf(vals[u]);
    }
  }

  // ---- biases -> LDS (keeps the main loop free of global loads; a global
  // load inside the loop would force an in-order vmcnt drain of the DMA ring)
#pragma unroll
  for (int v = 0; v < 4; v++) b1s[tid + v * 512] = b1A[tid + v * 512];
  bss[tid] = bsA[tid];
  bts[tid] = btA[tid];

  stage_seg(1, Bs[1], W1T, W2I, wave, lane, bxr, hswap);
  stage_seg(2, Bs[2], W1T, W2I, wave, lane, bxr, hswap);
  stage_seg(3, Bs[3], W1T, W2I, wave, lane, bxr, hswap);

  float jr[4] = {0.f, 0.f, 0.f, 0.f};
  bf16x8 af1[4];
  const f32x4 z = {0.f, 0.f, 0.f, 0.f};
  f32x4 acc2[4];

  for (int gs = 0; gs < 96; gs++) {
    // Counted wait: segs gs+1..gs+3 (2 events each) may stay in flight; gs
    // and older must retire (in-order vmcnt). Tail steps down 6->4->2->0.
    // Single asm: nothing (esp. ds_reads) slips between wait and barrier.
    if (gs < 93)
      asm volatile("s_waitcnt vmcnt(6) lgkmcnt(0)\n\ts_barrier" ::: "memory");
    else if (gs == 93)
      asm volatile("s_waitcnt vmcnt(4) lgkmcnt(0)\n\ts_barrier" ::: "memory");
    else if (gs == 94)
      asm volatile("s_waitcnt vmcnt(2) lgkmcnt(0)\n\ts_barrier" ::: "memory");
    else
      asm volatile("s_waitcnt vmcnt(0) lgkmcnt(0)\n\ts_barrier" ::: "memory");

    // ring-safe prefetch: buffer (gs+4)%5 == (gs-1)%5 was last read in
    // compute(gs-1), which completed before the barrier above.
    if (gs + 4 < 96) stage_seg(gs + 4, Bs[(gs + 4) % 5], W1T, W2I, wave, lane, bxr, hswap);

    // ---- compute segment gs
    const int l = gs / 24, s = gs % 24, typ = s % 3;
    const int nc8 = ((s / 3) + bxr) & 7;      // rotated chunk (bias index only)
    const unsigned short* B = Bs[gs % 5];
    unsigned short* XA = Xb[l & 1];
    unsigned short* XB = Xb[1 - (l & 1)];

    if (typ == 0) {                           // GEMM1 chunk: 64 h-cols, K=128
      if (s == 0) {                           // layer start: load A-frags, zero acc2
#pragma unroll
        for (int kw = 0; kw < 4; kw++) {
          const int kch = kw * 4 + q;
          af1[kw] = *(const bf16x8*)(XA + ((kch >> 3) * 32 + rg * 16 + c) * 64 +
                                     (((kch & 7) ^ (c & 7)) * 8));
        }
#pragma unroll
        for (int j = 0; j < 4; j++) acc2[j] = z;
      }
      f32x4 acc1 = z;
      const int rb = cg * 16 + c;             // h-col within 64-chunk
#pragma unroll
      for (int kw = 0; kw < 4; kw++) {
        const int kseg = kw >> 1, g = (kw & 1) * 4 + q;
        const bf16x8 bf = *(const bf16x8*)(B + (kseg * 64 + rb) * 64 + ((g ^ (rb & 7)) * 8));
        acc1 = __builtin_amdgcn_mfma_f32_16x16x32_bf16(af1[kw], bf, acc1, 0, 0, 0);
      }
      const int hc = cg * 16 + c;
      const float bb = b1s[l * NHID + nc8 * 64 + hc];   // LDS, not global
#pragma unroll
      for (int r = 0; r < 4; r++) {
        float v = acc1[r] + bb;
        v = v > 0.f ? v : 0.f;
        Hs[swadr(0, 32, rg * 16 + 4 * q + r, hc)] = f2bf(v);
      }
    } else {                                  // GEMM2: K=32 slice of this h chunk
      const int half = (typ - 1) ^ hswap;     // matches staged slice
      const bf16x8 afh = *(const bf16x8*)(Hs + (rg * 16 + c) * 64 +
                                          (((half * 4 + q) ^ (c & 7)) * 8));
#pragma unroll
      for (int j = 0; j < 4; j++) {
        const int rb = cg * 64 + 16 * j + c;
        const bf16x8 bf = *(const bf16x8*)(B + rb * 32 + ((q ^ ((rb >> 1) & 3)) * 8));
        acc2[j] = __builtin_amdgcn_mfma_f32_16x16x32_bf16(afh, bf, acc2[j], 0, 0, 0);
      }
    }

    // ---- coupling epilogue at layer end (even col=s, odd col=t)
    if (s == 23) {
      const int parity = c & 1;
      const int lastl = (l == NLAY - 1);
      const float* bsl = bss + l * NHALF;     // LDS
      const float* btl = bts + l * NHALF;     // LDS
#pragma unroll
      for (int j = 0; j < 4; j++) {
        const int col = cg * 64 + 16 * j + c;
#pragma unroll
        for (int r = 0; r < 4; r++) {
          const float val = acc2[j][r];
          const float oth = __shfl_xor(val, 1);   // all lanes participate
          if (!parity) {
            const int feat = col >> 1;
            float sv = val + bsl[feat];
            if (!lastl) sv = fast_tanh(sv);
            const float t = oth + btl[feat];
            const int row = rg * 16 + 4 * q + r;
            const int xaddr = swadr(feat >> 6, 32, row, feat & 63);
            const float xb = bf2f(XB[xaddr]);
            const float yb = xb * __expf(sv) + t;
            jr[r] += sv;
            XB[xaddr] = f2bf(yb);                 // in-place: same owner thread
            if (l >= 2) {
              const int k = lastl ? feat : (NHALF + feat);
              const size_t grow = (size_t)(m0 + row) * NF;
              xout[grow + k] = yb;
              xf8[(size_t)(m0 + row) * 256 + k] = f2fp8(yb * SX);  // natural order
            }
          }
        }
      }
    }
  }

  // jac: reduce 16 c-lanes in-wave, park per-(cg) partials in LDS, then sum
#pragma unroll
  for (int r = 0; r < 4; r++) {
    float v = jr[r];
    v += __shfl_xor(v, 1); v += __shfl_xor(v, 2);
    v += __shfl_xor(v, 4); v += __shfl_xor(v, 8);
    if (c == 0) jlds[cg][rg * 16 + 4 * q + r] = v;
  }
  __syncthreads();
  if (tid < 32)
    jac[m0 + tid] = jlds[0][tid] + jlds[1][tid] + jlds[2][tid] + jlds[3][tid];
}

// ---------------------------------------------------------------- VQ argmax (MX fp8)
// Grid 512: slice = bx & 15 (XCD-pinned), m-group = bx >> 4 (256 rows).
// mfma_scale_f32_16x16x128_f8f6f4 with unit e8m0 scales (0x7F = 2^0): the
// only large-K fp8 MFMA, ~2.3x the 16x16x32 fp8 rate. K=128 fragments = 32
// CONTIGUOUS k-bytes per lane -> X8/P8 in NATURAL k order. Correct under any
// internal k-permutation: A and B lane layouts are mirrored, so a shared
// permutation of k leaves the dot product invariant. -0.5||p||^2 folded into
// the accumulator init (C-in = -nb).
__global__ __launch_bounds__(256, 2)
void vq_argmax(const unsigned char* __restrict__ X8,   // [NB][256] fp8, natural k
               const unsigned char* __restrict__ P8,   // [NK][256] fp8, natural k
               const float* __restrict__ nbh,          // [NK] scaled 0.5||p||^2
               unsigned long long* __restrict__ gbest) // [NB] packed
{
  __shared__ __align__(16) unsigned char Bs[2][64 * 256];  // 2x16 KB
  const int tid = threadIdx.x;
  const int lane = tid & 63, wave = tid >> 6;
  const int y = blockIdx.x & 15;
  const int m0 = (blockIdx.x >> 4) * 256;
  const int q = lane >> 4, c = lane & 15;
  const int mw = m0 + wave * 64;
  const int one = 0x7F7F7F7F;                // e8m0 scale 1.0 in every byte

  // A-frags: 64 rows/wave x 256 k-bytes; lane (q,c): row 16i+c, half h,
  // bytes [h*128 + q*32, +32) -> i32x8
  i32x8 af[4][2];
#pragma unroll
  for (int i = 0; i < 4; i++) {
    const unsigned char* xr = X8 + (size_t)(mw + 16 * i + c) * 256 + q * 32;
#pragma unroll
    for (int h = 0; h < 2; h++) {
      const int4 lo = *(const int4*)(xr + h * 128);
      const int4 hi = *(const int4*)(xr + h * 128 + 16);
      af[i][h] = (i32x8){lo.x, lo.y, lo.z, lo.w, hi.x, hi.y, hi.z, hi.w};
    }
  }

  float bestv[16];
  int besti[16];
#pragma unroll
  for (int t = 0; t < 16; t++) { bestv[t] = -1e30f; besti[t] = 0; }

  // stage tile 0: slot (row,gslot) holds src chunk gslot^(row&15)
  {
    const int n0s = y * 2048;
#pragma unroll
    for (int u = 0; u < 4; u++) {
      const int chb = (u * 4 + wave) * 64;
      const int ch = chb + lane;
      const int row = ch >> 4, gslot = ch & 15;
      load_lds16(P8 + (size_t)(n0s + row) * 256 + (gslot ^ (row & 15)) * 16,
                 Bs[0] + chb * 16);
    }
  }

  for (int nt = 0; nt < 32; nt++) {
    const int n0 = y * 2048 + nt * 64;
    __syncthreads();     // DMA(nt) landed; prev reads of the other buffer done

    // hoist -0.5||p||^2 terms (issued BEFORE the next DMA -> no ring drain)
    float nbr[4];
#pragma unroll
    for (int j = 0; j < 4; j++) nbr[j] = nbh[n0 + 16 * j + c];

    if (nt + 1 < 32) {                        // prefetch tile nt+1
      const int n0s = n0 + 64;
      unsigned char* dst = Bs[(nt + 1) & 1];
#pragma unroll
      for (int u = 0; u < 4; u++) {
        const int chb = (u * 4 + wave) * 64;
        const int ch = chb + lane;
        const int row = ch >> 4, gslot = ch & 15;
        load_lds16(P8 + (size_t)(n0s + row) * 256 + (gslot ^ (row & 15)) * 16,
                   dst + chb * 16);
      }
    }

    const unsigned char* Bt = Bs[nt & 1];
    f32x4 acc[4][4];
#pragma unroll
    for (int i = 0; i < 4; i++)
#pragma unroll
      for (int j = 0; j < 4; j++)
        acc[i][j] = (f32x4){-nbr[j], -nbr[j], -nbr[j], -nbr[j]};

#pragma unroll
    for (int j = 0; j < 4; j++) {
      const unsigned char* base = Bt + (16 * j + c) * 256;
#pragma unroll
      for (int h = 0; h < 2; h++) {
        // B-frag: code row 16j+c, k-bytes [h*128 + q*32, +32), chunk-XOR swz
        const int4 b0 = *(const int4*)(base + ((8 * h + 2 * q)     ^ c) * 16);
        const int4 b1 = *(const int4*)(base + ((8 * h + 2 * q + 1) ^ c) * 16);
        const i32x8 bf = (i32x8){b0.x, b0.y, b0.z, b0.w, b1.x, b1.y, b1.z, b1.w};
#pragma unroll
        for (int i = 0; i < 4; i++)
          acc[i][j] = __builtin_amdgcn_mfma_scale_f32_16x16x128_f8f6f4(
              af[i][h], bf, acc[i][j], 0, 0, 0, one, 0, one);
      }
    }

    // lane-local running argmax; sc already includes -nb via C-init
#pragma unroll
    for (int j = 0; j < 4; j++) {
      const int col = n0 + 16 * j + c;
#pragma unroll
      for (int i = 0; i < 4; i++)
#pragma unroll
        for (int r = 0; r < 4; r++) {
          const float sc = acc[i][j][r];
          const int t = i * 4 + r;
          if (sc > bestv[t]) { bestv[t] = sc; besti[t] = col; }
        }
    }
  }

  // reduce across 16 c-lanes per slot; rows unique per (wave, i, q, r)
#pragma unroll
  for (int t = 0; t < 16; t++) {
    float lv = bestv[t]; int li = besti[t];
#pragma unroll
    for (int mk = 8; mk >= 1; mk >>= 1) {
      const float ov = __shfl_xor(lv, mk);
      const int oi = __shfl_xor(li, mk);
      if (ov > lv || (ov == lv && oi < li)) { lv = ov; li = oi; }
    }
    if (c == 0) {
      const int row = mw + 16 * (t >> 2) + q * 4 + (t & 3);
      atomicMax(&gbest[row], packsi(lv, li));
    }
  }
}

// ---------------------------------------------------------------- fused prep
// bx [0,2048): prior -> fp8 (scale SP, natural k order) + scaled nbh |
// [2048,2112): W1 transpose | [2112,2240): Ws/Wt -> W2I | [2240,2272): init
__global__ void prep_all(const float* __restrict__ W1,
                         const float* __restrict__ Ws,
                         const float* __restrict__ Wt,
                         const float* __restrict__ prior,
                         unsigned short* __restrict__ W1T,
                         unsigned short* __restrict__ W2I,
                         unsigned char* __restrict__ p8,
                         float* __restrict__ nbh,
                         unsigned long long* __restrict__ gbest,
                         float* __restrict__ accum)
{
  __shared__ float ts[64 * 65];
  const int bx = blockIdx.x;
  const int tid = threadIdx.x;
  if (bx < 2048) {
    const int k = bx * 16 + (tid >> 4);      // code index
    const int l16 = tid & 15;
    float s = 0.f;
#pragma unroll
    for (int v = 0; v < 4; v++) {
      const int off = (v * 16 + l16) * 4;    // k-offset, multiple of 4
      const float4 d = *(const float4*)(prior + (size_t)k * NF + off);
      uchar4 o;
      o.x = f2fp8(d.x * SP); o.y = f2fp8(d.y * SP);
      o.z = f2fp8(d.z * SP); o.w = f2fp8(d.w * SP);
      *(uchar4*)(p8 + (size_t)k * 256 + off) = o;          // natural order
      const float q0 = fp82f(o.x), q1 = fp82f(o.y), q2 = fp82f(o.z), q3 = fp82f(o.w);
      s += q0 * q0 + q1 * q1 + q2 * q2 + q3 * q3;
    }
#pragma unroll
    for (int mk = 8; mk >= 1; mk >>= 1) s += __shfl_xor(s, mk);
    if (l16 == 0) nbh[k] = 0.5f * s * (SX / SP);   // consistent scaled domain
  } else if (bx < 2112) {
    const int job = bx - 2048;
    const int l = job >> 4, t = job & 15;
    const int k0 = (t >> 3) * 64, n0 = (t & 7) * 64;
    const float* src = W1 + (size_t)l * NHALF * NHID;
#pragma unroll
    for (int v = 0; v < 16; v++) {
      const int e = tid + v * 256;
      const int kk = e >> 6, nn = e & 63;
      ts[kk * 65 + nn] = src[(size_t)(k0 + kk) * NHID + n0 + nn];
    }
    __syncthreads();
    unsigned short* dst = W1T + (size_t)l * NHID * NHALF;
#pragma unroll
    for (int v = 0; v < 16; v++) {
      const int e = tid + v * 256;
      const int nn = e >> 6, kk = e & 63;
      dst[(size_t)(n0 + nn) * NHALF + k0 + kk] = f2bf(ts[kk * 65 + nn]);
    }
  } else if (bx < 2240) {
    const int job = bx - 2112;
    const int l = job >> 5, rem = job & 31;
    const int b = rem >> 4;
    const int k0 = ((rem >> 1) & 7) * 64;
    const int f0 = (rem & 1) * 64;
    const float* src = (b ? Wt : Ws) + (size_t)l * NHID * NHALF;
#pragma unroll
    for (int v = 0; v < 16; v++) {
      const int e = tid + v * 256;
      const int kk = e >> 6, nn = e & 63;
      ts[kk * 65 + nn] = src[(size_t)(k0 + kk) * NHALF + f0 + nn];
    }
    __syncthreads();
#pragma unroll
    for (int v = 0; v < 16; v++) {
      const int e = tid + v * 256;
      const int nn = e >> 6, kk = e & 63;
      W2I[((size_t)l * NF + 2 * (f0 + nn) + b) * NHID + k0 + kk] = f2bf(ts[kk * 65 + nn]);
    }
  } else {
    const int idx = (bx - 2240) * 256 + tid;
    if (idx < NB) gbest[idx] = 0ull;
    if (idx < 4) accum[idx] = 0.f;    // [0]=dist [1]=jac [2]=ticket [3]=spare
  }
}

// ---------------------------------------------------------------- VQ finalize (+ fused loss)
// Last-arriving block (device-scope ticket on accum[2]) computes the scalar
// loss; accumulators read back via atomicAdd(p, 0) for cross-XCD coherence.
__global__ void vq_finalize(const float* __restrict__ X,      // d_out x, fp32
                            const float* __restrict__ prior,
                            const unsigned long long* __restrict__ gbest,
                            const float* __restrict__ jac,
                            float* __restrict__ accum,        // [0]=dist,[1]=jac,[2]=ticket
                            float* __restrict__ loss)
{
  const int wave = threadIdx.x >> 6, lane = threadIdx.x & 63;
  const int gw = blockIdx.x * 4 + wave;        // 1024 waves, 8 rows each
  float accd = 0.f, accj = 0.f;
  for (int r = 0; r < 8; r++) {
    const int row = gw * 8 + r;
    const unsigned int idx = ~(unsigned int)(gbest[row]);   // low 32 bits = ~idx
    const float* x = X + (size_t)row * NF;
    const float* p = prior + (size_t)idx * NF;
#pragma unroll
    for (int u = 0; u < 4; u++) {
      const int d = lane + u * 64;
      const float df = x[d] - p[d];
      accd += df * df;
    }
    if (lane == 0) accj += jac[row];
  }
#pragma unroll
  for (int mk = 32; mk >= 1; mk >>= 1) {
    accd += __shfl_xor(accd, mk);
    accj += __shfl_xor(accj, mk);
  }
  __shared__ float sd[4], sj[4];
  if (lane == 0) { sd[wave] = accd; sj[wave] = accj; }
  __syncthreads();
  if (threadIdx.x == 0) {
    atomicAdd(&accum[0], sd[0] + sd[1] + sd[2] + sd[3]);
    atomicAdd(&accum[1], sj[0] + sj[1] + sj[2] + sj[3]);
    __threadfence();                                        // release our adds
    const unsigned int t = atomicAdd((unsigned int*)&accum[2], 1u);
    if (t == 255u) {                                        // last of 256 blocks
      const float d = atomicAdd(&accum[0], 0.f);            // coherent read
      const float jv = atomicAdd(&accum[1], 0.f);
      loss[0] = 1.25f * (0.5f * d / (float)NB) - jv / (float)NB;
    }
  }
}

// ---------------------------------------------------------------- launch
extern "C" void kernel_launch(void* const* d_in, const int* in_sizes, int n_in,
                              void* d_out, int out_size, void* d_ws, size_t ws_size,
                              hipStream_t stream)
{
  (void)in_sizes; (void)n_in; (void)out_size; (void)ws_size;
  const float* inputs = (const float*)d_in[0];
  const float* W1 = (const float*)d_in[1];
  const float* b1 = (const float*)d_in[2];
  const float* Ws = (const float*)d_in[3];
  const float* bs = (const float*)d_in[4];
  const float* Wt = (const float*)d_in[5];
  const float* bt = (const float*)d_in[6];
  const float* prior = (const float*)d_in[7];

  char* p = (char*)d_ws;
  auto alloc = [&](size_t bytes) { char* r = p; p += (bytes + 255) & ~(size_t)255; return r; };
  unsigned short* W1T  = (unsigned short*)alloc((size_t)NLAY * NHID * NHALF * 2);
  unsigned short* W2I  = (unsigned short*)alloc((size_t)NLAY * NF * NHID * 2);
  unsigned char* P8    = (unsigned char*)alloc((size_t)NK * 256);
  float* NBH           = (float*)alloc((size_t)NK * 4);
  unsigned char* XF8   = (unsigned char*)alloc((size_t)NB * 256);
  float* JAC           = (float*)alloc((size_t)NB * 4);
  unsigned long long* GBEST = (unsigned long long*)alloc((size_t)NB * 8);
  float* ACC           = (float*)alloc(256);

  float* xout = (float*)d_out;                 // [NB][NF]
  float* loss = xout + (size_t)NB * NF;        // scalar

  prep_all<<<dim3(2272), 256, 0, stream>>>(
      W1, Ws, Wt, prior, W1T, W2I, P8, NBH, GBEST, ACC);

  flow_all<<<dim3(NB / 32), 512, 0, stream>>>(
      inputs, W1T, W2I, b1, bs, bt, xout, XF8, JAC);

  vq_argmax<<<dim3(32 * 16), 256, 0, stream>>>(XF8, P8, NBH, GBEST);
  vq_finalize<<<dim3(256), 256, 0, stream>>>(xout, prior, GBEST, JAC, ACC, loss);
}

// Round 4
// 237.428 us; speedup vs baseline: 1.2323x; 1.0825x over previous
//
#include <hip/hip_runtime.h>
#include <hip/hip_fp8.h>
#include <stdint.h>

// ---------------------------------------------------------------- constants
#define NB     8192     // batch
#define NF     256      // features
#define NHALF  128      // F/2
#define NHID   512      // hidden = 2F
#define NLAY   4        // coupling layers
#define NK     32768    // codebook size

#define SX     (1.0f / 16.0f)    // x scale for fp8 (|x|<=474/16=30 < 448)
#define SP     (256.0f)          // p scale for fp8 (Glorot +-0.0135*256=3.46)

typedef __attribute__((ext_vector_type(8))) short bf16x8;   // 8 bf16 = 4 VGPR
typedef __attribute__((ext_vector_type(4))) float f32x4;
typedef __attribute__((ext_vector_type(8))) int i32x8;      // 32 B MX fp8 frag

static __device__ __forceinline__ unsigned short f2bf(float f) {
  union { float f; unsigned int u; } v; v.f = f;
  return (unsigned short)((v.u + 0x7FFFu + ((v.u >> 16) & 1u)) >> 16);  // RNE
}
static __device__ __forceinline__ float bf2f(unsigned short u) {
  union { unsigned int u; float f; } v; v.u = ((unsigned int)u) << 16; return v.f;
}
static __device__ __forceinline__ unsigned char f2fp8(float f) {
  __hip_fp8_e4m3 q(f);                       // OCP e4m3fn, RNE + saturate
  return (unsigned char)q.__x;
}
static __device__ __forceinline__ float fp82f(unsigned char b) {
  __hip_fp8_e4m3 q; q.__x = b; return (float)q;
}

// async global->LDS, 16B per lane; LDS dest = wave-uniform base + lane*16
static __device__ __forceinline__ void load_lds16(const void* g, void* l) {
  __builtin_amdgcn_global_load_lds(
      (const __attribute__((address_space(1))) unsigned int*)g,
      (__attribute__((address_space(3))) unsigned int*)l, 16, 0, 0);
}

// pack (score, idx) so u64 max == argmax with smallest-index tiebreak
static __device__ __forceinline__ unsigned long long packsi(float v, int idx) {
  unsigned int b = __float_as_uint(v);
  b = (b & 0x80000000u) ? ~b : (b | 0x80000000u);   // order-preserving map
  return ((unsigned long long)b << 32) | (unsigned int)(~(unsigned int)idx);
}

static __device__ __forceinline__ float fast_tanh(float x) {
  const float xc = fminf(fmaxf(x, -15.f), 15.f);
  const float e2 = __expf(2.f * xc);
  return 1.f - 2.f / (e2 + 1.f);
}

// Xb tile address: [kseg][row][64 shorts], 3-bit XOR chunk swizzle (proven
// 0-conflict for the af1/epilogue patterns).
static __device__ __forceinline__ int swadr(int kseg, int nrows, int row, int kin) {
  return (kseg * nrows + row) * 64 + (((kin >> 3) ^ (row & 7)) * 8) + (kin & 7);
}

// W1 16-B-slot swizzle: g1(row) = (row&15) ^ ((row&8)>>1). The extra bit-3->
// bit-2 fold puts reader bank-quad = uniform 8 lanes/quad (without it the
// A1 read concentrates 16 lanes on 4 quads = 2x LDS cost).
static __device__ __forceinline__ int g1swz(int row) {
  return (row & 15) ^ ((row & 8) >> 1);
}

// stage one 48 KB chunk-unit g (of 32): W1 chunk [64 h][128 k] (16 KB,
// 16-B slots XOR g1swz(row)) + W2 chunk [256 cols][64 k] (32 KB, 16-B slots
// XOR (col&7)). PER-BLOCK DECORRELATION: chunk order rotated by bxr (8
// address-phase groups per XCD); legal since GEMM2 accumulates chunks in any
// order. Each WAVE issues exactly 6 vmcnt events (2 W1 + 4 W2), fixed order.
static __device__ __forceinline__ void stage_chunk(
    int g, unsigned short* dst,
    const unsigned short* __restrict__ W1T,
    const unsigned short* __restrict__ W2I,
    int wave, int lane, int bxr)
{
  const int l = g >> 3;
  const int nc = ((g & 7) + bxr) & 7;
  const unsigned short* W1l = W1T + (size_t)l * (NHID * NHALF) + (size_t)nc * 64 * 128;
#pragma unroll
  for (int u = 0; u < 2; u++) {
    const int ch = (u * 8 + wave) * 64 + lane;       // 16-B unit, 0..1023
    const int row = ch >> 4, sl = ch & 15;
    load_lds16(W1l + (size_t)row * 128 + (sl ^ g1swz(row)) * 8, dst + ch * 8);
  }
  const unsigned short* W2l = W2I + (size_t)l * (NF * NHID) + nc * 64;
#pragma unroll
  for (int u = 0; u < 4; u++) {
    const int ch = (u * 8 + wave) * 64 + lane;       // 16-B unit, 0..2047
    const int col = ch >> 3, sl = ch & 7;
    load_lds16(W2l + (size_t)col * NHID + ((sl ^ (col & 7)) * 8),
               dst + 8192 + ch * 8);
  }
}

// ---------------------------------------------------------------- fused flow (ALL 4 layers)
// ONE 512-thread block per CU (grid 256, 32 rows). REDESIGN vs R3: the H
// round-trip through LDS is GONE. GEMM1 computes D1 = W1^T . X (swapped
// operands) with an interleaved h-assignment sigma(m)=8*(m>>2)+(m&3)+4*tb,
// so two 16-row GEMM1 tiles concatenate IN REGISTERS into the exact K=32
// A-fragment of GEMM2 (k=8q+e). Each wave redundantly computes all 64 h-cols
// of its chunk (4x duplicate GEMM1 MFMA -- cheap at 5% MfmaUtil) so its
// GEMM2 depends only on its own registers: NO interior barrier, NO Hs.
// 32 chunk-iterations x 2 barriers (counted vmcnt(6) TOP + bare-lgkm BAR2
// protecting the 2x48KB ring) vs R3's 96 drain-y segments.
__global__ __launch_bounds__(512, 2)
void flow_all(const float* __restrict__ in,
              const unsigned short* __restrict__ W1T,   // [L][512 h][128 k]
              const unsigned short* __restrict__ W2I,   // [L][256 col][512 k]
              const float* __restrict__ b1A,
              const float* __restrict__ bsA,
              const float* __restrict__ btA,
              float* __restrict__ xout,
              unsigned char* __restrict__ xf8,          // [NB][256] fp8(x*SX)
              float* __restrict__ jac)
{
  __shared__ __align__(16) unsigned short Xb[2][32 * 128];   // 16 KB x-state
  __shared__ __align__(16) unsigned short Bs[2][24576];      // 96 KB ring (2x48KB)
  __shared__ float b1s[NLAY * NHID];                         //  8 KB bias
  __shared__ float bss[NLAY * NHALF];                        //  2 KB
  __shared__ float bts[NLAY * NHALF];                        //  2 KB
  __shared__ float jlds[4][32];
  const int tid = threadIdx.x;
  const int lane = tid & 63, wave = tid >> 6;
  const int rg = wave >> 2, cg = wave & 3;     // row-group, col-group
  const int q = lane >> 4, c = lane & 15;
  const int m0 = blockIdx.x * 32;
  const int bxr = blockIdx.x & 7;

  // DMA(chunk 0) first: maximum latency cover
  stage_chunk(0, Bs[0], W1T, W2I, wave, lane, bxr);

  // ---- init x-state: Xb[0]=bf16(in[:, :128]) (xa0), Xb[1]=bf16(in[:,128:])
#pragma unroll
  for (int v = 0; v < 4; v++) {
    const int t4 = tid + v * 512;            // 2048 float4s = 32 rows x 64
    const int row = t4 >> 6, f4 = t4 & 63;
    const float4 d = *(const float4*)(in + (size_t)(m0 + row) * NF + f4 * 4);
    unsigned short* dst = Xb[f4 >> 5];
    const int feat = (f4 & 31) * 4;
    const float vals[4] = {d.x, d.y, d.z, d.w};
#pragma unroll
    for (int u = 0; u < 4; u++) {
      const int fe = feat + u;
      dst[swadr(fe >> 6, 32, row, fe & 63)] = f2bf(vals[u]);
    }
  }

  // ---- biases -> LDS (keeps the main loop free of compiler-tracked global
  // LOADS so the counted vmcnt stays exact; only epilogue STORES remain,
  // which the in-order vmcnt(6) wait drains harmlessly)
#pragma unroll
  for (int v = 0; v < 4; v++) b1s[tid + v * 512] = b1A[tid + v * 512];
  bss[tid] = bsA[tid];
  bts[tid] = btA[tid];

  stage_chunk(1, Bs[1], W1T, W2I, wave, lane, bxr);

  float jr[4] = {0.f, 0.f, 0.f, 0.f};
  bf16x8 af1[4];
  const f32x4 z = {0.f, 0.f, 0.f, 0.f};
  f32x4 acc2[4];

  for (int g = 0; g < 32; g++) {
    // TOP: counted wait. In flight: chunk g (oldest 6) + chunk g+1 (6)
    // [+ epilogue stores, older than g+1's stage -> also drained].
    // vmcnt(6) proves chunk g landed; chunk g+1 streams across the barrier.
    if (g < 31)
      asm volatile("s_waitcnt vmcnt(6) lgkmcnt(0)\n\ts_barrier" ::: "memory");
    else
      asm volatile("s_waitcnt vmcnt(0) lgkmcnt(0)\n\ts_barrier" ::: "memory");

    const int l = g >> 3, s = g & 7;
    const int nc = (s + bxr) & 7;              // rotated chunk id
    const unsigned short* B = Bs[g & 1];       // W1 part at 0, W2 at +8192
    const unsigned short* W2B = B + 8192;
    unsigned short* XA = Xb[l & 1];
    unsigned short* XB = Xb[1 - (l & 1)];

    if (s == 0) {                              // layer start: X frags, zero acc
#pragma unroll
      for (int kw = 0; kw < 4; kw++) {
        const int kch = kw * 4 + q;
        af1[kw] = *(const bf16x8*)(XA + ((kch >> 3) * 32 + rg * 16 + c) * 64 +
                                   (((kch & 7) ^ (c & 7)) * 8));
      }
#pragma unroll
      for (int j = 0; j < 4; j++) acc2[j] = z;
    }

    const int bias_base = l * NHID + nc * 64;
#pragma unroll
    for (int P = 0; P < 2; P++) {              // two 32-k windows per chunk
      union { unsigned int u[4]; bf16x8 v; } a2;
#pragma unroll
      for (int tb = 0; tb < 2; tb++) {         // interleaved h-tiles A,B
        f32x4 acc1 = z;
        const int row = P * 32 + 8 * (c >> 2) + (c & 3) + 4 * tb;  // sigma(c)
        const int gsw = g1swz(row);
#pragma unroll
        for (int kk = 0; kk < 4; kk++) {
          // A1-frag: W1[h=row][k=kk*32+8q+e]
          const bf16x8 a1 = *(const bf16x8*)(B + row * 128 +
                                             (((kk * 4 + q) ^ gsw) * 8));
          acc1 = __builtin_amdgcn_mfma_f32_16x16x32_bf16(a1, af1[kk], acc1, 0, 0, 0);
        }
        // D1: lane (q,c) holds h = P*32 + 8q + 4tb + r for batch col c.
        // bias is uniform in c -> LDS broadcast (f32x4, 16-B aligned).
        const float4 bb = *(const float4*)(b1s + bias_base + P * 32 + 8 * q + 4 * tb);
        const float v0 = fmaxf(acc1[0] + bb.x, 0.f);
        const float v1 = fmaxf(acc1[1] + bb.y, 0.f);
        const float v2 = fmaxf(acc1[2] + bb.z, 0.f);
        const float v3 = fmaxf(acc1[3] + bb.w, 0.f);
        a2.u[tb * 2]     = (unsigned int)f2bf(v0) | ((unsigned int)f2bf(v1) << 16);
        a2.u[tb * 2 + 1] = (unsigned int)f2bf(v2) | ((unsigned int)f2bf(v3) << 16);
      }
      // a2.v is the exact K=32 A-frag (k = 8q+e -> h = P*32+8q+e): e<4 from
      // tile A (offset +0), e>=4 from tile B (offset +4). Zero shuffles.
#pragma unroll
      for (int j = 0; j < 4; j++) {
        const int col = cg * 64 + 16 * j + c;
        const bf16x8 b2 = *(const bf16x8*)(W2B + col * 64 +
                                           (((P * 4 + q) ^ (col & 7)) * 8));
        acc2[j] = __builtin_amdgcn_mfma_f32_16x16x32_bf16(a2.v, b2, acc2[j], 0, 0, 0);
      }
    }

    // ---- coupling epilogue at layer end (even col=s, odd col=t)
    if (s == 7) {
      const int parity = c & 1;
      const int lastl = (l == NLAY - 1);
      const float* bsl = bss + l * NHALF;     // LDS
      const float* btl = bts + l * NHALF;     // LDS
#pragma unroll
      for (int j = 0; j < 4; j++) {
        const int col = cg * 64 + 16 * j + c;
#pragma unroll
        for (int r = 0; r < 4; r++) {
          const float val = acc2[j][r];
          const float oth = __shfl_xor(val, 1);   // all lanes participate
          if (!parity) {
            const int feat = col >> 1;
            float sv = val + bsl[feat];
            if (!lastl) sv = fast_tanh(sv);
            const float t = oth + btl[feat];
            const int row = rg * 16 + 4 * q + r;
            const int xaddr = swadr(feat >> 6, 32, row, feat & 63);
            const float xb = bf2f(XB[xaddr]);
            const float yb = xb * __expf(sv) + t;
            jr[r] += sv;
            XB[xaddr] = f2bf(yb);                 // in-place: same owner thread
            if (l >= 2) {
              const int k = lastl ? feat : (NHALF + feat);
              const size_t grow = (size_t)(m0 + row) * NF;
              xout[grow + k] = yb;
              xf8[(size_t)(m0 + row) * 256 + k] = f2fp8(yb * SX);
            }
          }
        }
      }
    }

    // BAR2: all waves done reading Bs[g&1] (their ds_reads were consumed by
    // MFMAs -> lgkm drained); then overwrite it with chunk g+2's DMA.
    asm volatile("s_waitcnt lgkmcnt(0)\n\ts_barrier" ::: "memory");
    if (g + 2 < 32) stage_chunk(g + 2, Bs[g & 1], W1T, W2I, wave, lane, bxr);
  }

  // jac: reduce 16 c-lanes in-wave, park per-(cg) partials in LDS, then sum
#pragma unroll
  for (int r = 0; r < 4; r++) {
    float v = jr[r];
    v += __shfl_xor(v, 1); v += __shfl_xor(v, 2);
    v += __shfl_xor(v, 4); v += __shfl_xor(v, 8);
    if (c == 0) jlds[cg][rg * 16 + 4 * q + r] = v;
  }
  __syncthreads();
  if (tid < 32)
    jac[m0 + tid] = jlds[0][tid] + jlds[1][tid] + jlds[2][tid] + jlds[3][tid];
}

// ---------------------------------------------------------------- VQ argmax (MX fp8)
// Grid 512: slice = bx & 15 (XCD-pinned), m-group = bx >> 4 (256 rows).
// mfma_scale_f32_16x16x128_f8f6f4 with unit e8m0 scales (0x7F = 2^0): the
// only large-K fp8 MFMA, ~2.3x the 16x16x32 fp8 rate. K=128 fragments = 32
// CONTIGUOUS k-bytes per lane -> X8/P8 in NATURAL k order. Correct under any
// internal k-permutation: A and B lane layouts are mirrored, so a shared
// permutation of k leaves the dot product invariant. -0.5||p||^2 folded into
// the accumulator init (C-in = -nb).
__global__ __launch_bounds__(256, 2)
void vq_argmax(const unsigned char* __restrict__ X8,   // [NB][256] fp8, natural k
               const unsigned char* __restrict__ P8,   // [NK][256] fp8, natural k
               const float* __restrict__ nbh,          // [NK] scaled 0.5||p||^2
               unsigned long long* __restrict__ gbest) // [NB] packed
{
  __shared__ __align__(16) unsigned char Bs[2][64 * 256];  // 2x16 KB
  const int tid = threadIdx.x;
  const int lane = tid & 63, wave = tid >> 6;
  const int y = blockIdx.x & 15;
  const int m0 = (blockIdx.x >> 4) * 256;
  const int q = lane >> 4, c = lane & 15;
  const int mw = m0 + wave * 64;
  const int one = 0x7F7F7F7F;                // e8m0 scale 1.0 in every byte

  // A-frags: 64 rows/wave x 256 k-bytes; lane (q,c): row 16i+c, half h,
  // bytes [h*128 + q*32, +32) -> i32x8
  i32x8 af[4][2];
#pragma unroll
  for (int i = 0; i < 4; i++) {
    const unsigned char* xr = X8 + (size_t)(mw + 16 * i + c) * 256 + q * 32;
#pragma unroll
    for (int h = 0; h < 2; h++) {
      const int4 lo = *(const int4*)(xr + h * 128);
      const int4 hi = *(const int4*)(xr + h * 128 + 16);
      af[i][h] = (i32x8){lo.x, lo.y, lo.z, lo.w, hi.x, hi.y, hi.z, hi.w};
    }
  }

  float bestv[16];
  int besti[16];
#pragma unroll
  for (int t = 0; t < 16; t++) { bestv[t] = -1e30f; besti[t] = 0; }

  // stage tile 0: slot (row,gslot) holds src chunk gslot^(row&15)
  {
    const int n0s = y * 2048;
#pragma unroll
    for (int u = 0; u < 4; u++) {
      const int chb = (u * 4 + wave) * 64;
      const int ch = chb + lane;
      const int row = ch >> 4, gslot = ch & 15;
      load_lds16(P8 + (size_t)(n0s + row) * 256 + (gslot ^ (row & 15)) * 16,
                 Bs[0] + chb * 16);
    }
  }

  for (int nt = 0; nt < 32; nt++) {
    const int n0 = y * 2048 + nt * 64;
    __syncthreads();     // DMA(nt) landed; prev reads of the other buffer done

    // hoist -0.5||p||^2 terms (issued BEFORE the next DMA -> no ring drain)
    float nbr[4];
#pragma unroll
    for (int j = 0; j < 4; j++) nbr[j] = nbh[n0 + 16 * j + c];

    if (nt + 1 < 32) {                        // prefetch tile nt+1
      const int n0s = n0 + 64;
      unsigned char* dst = Bs[(nt + 1) & 1];
#pragma unroll
      for (int u = 0; u < 4; u++) {
        const int chb = (u * 4 + wave) * 64;
        const int ch = chb + lane;
        const int row = ch >> 4, gslot = ch & 15;
        load_lds16(P8 + (size_t)(n0s + row) * 256 + (gslot ^ (row & 15)) * 16,
                   dst + chb * 16);
      }
    }

    const unsigned char* Bt = Bs[nt & 1];
    f32x4 acc[4][4];
#pragma unroll
    for (int i = 0; i < 4; i++)
#pragma unroll
      for (int j = 0; j < 4; j++)
        acc[i][j] = (f32x4){-nbr[j], -nbr[j], -nbr[j], -nbr[j]};

#pragma unroll
    for (int j = 0; j < 4; j++) {
      const unsigned char* base = Bt + (16 * j + c) * 256;
#pragma unroll
      for (int h = 0; h < 2; h++) {
        // B-frag: code row 16j+c, k-bytes [h*128 + q*32, +32), chunk-XOR swz
        const int4 b0 = *(const int4*)(base + ((8 * h + 2 * q)     ^ c) * 16);
        const int4 b1 = *(const int4*)(base + ((8 * h + 2 * q + 1) ^ c) * 16);
        const i32x8 bf = (i32x8){b0.x, b0.y, b0.z, b0.w, b1.x, b1.y, b1.z, b1.w};
#pragma unroll
        for (int i = 0; i < 4; i++)
          acc[i][j] = __builtin_amdgcn_mfma_scale_f32_16x16x128_f8f6f4(
              af[i][h], bf, acc[i][j], 0, 0, 0, one, 0, one);
      }
    }

    // lane-local running argmax; sc already includes -nb via C-init
#pragma unroll
    for (int j = 0; j < 4; j++) {
      const int col = n0 + 16 * j + c;
#pragma unroll
      for (int i = 0; i < 4; i++)
#pragma unroll
        for (int r = 0; r < 4; r++) {
          const float sc = acc[i][j][r];
          const int t = i * 4 + r;
          if (sc > bestv[t]) { bestv[t] = sc; besti[t] = col; }
        }
    }
  }

  // reduce across 16 c-lanes per slot; rows unique per (wave, i, q, r)
#pragma unroll
  for (int t = 0; t < 16; t++) {
    float lv = bestv[t]; int li = besti[t];
#pragma unroll
    for (int mk = 8; mk >= 1; mk >>= 1) {
      const float ov = __shfl_xor(lv, mk);
      const int oi = __shfl_xor(li, mk);
      if (ov > lv || (ov == lv && oi < li)) { lv = ov; li = oi; }
    }
    if (c == 0) {
      const int row = mw + 16 * (t >> 2) + q * 4 + (t & 3);
      atomicMax(&gbest[row], packsi(lv, li));
    }
  }
}

// ---------------------------------------------------------------- fused prep
// bx [0,2048): prior -> fp8 (scale SP, natural k order) + scaled nbh |
// [2048,2112): W1 transpose | [2112,2240): Ws/Wt -> W2I | [2240,2272): init
__global__ void prep_all(const float* __restrict__ W1,
                         const float* __restrict__ Ws,
                         const float* __restrict__ Wt,
                         const float* __restrict__ prior,
                         unsigned short* __restrict__ W1T,
                         unsigned short* __restrict__ W2I,
                         unsigned char* __restrict__ p8,
                         float* __restrict__ nbh,
                         unsigned long long* __restrict__ gbest,
                         float* __restrict__ accum)
{
  __shared__ float ts[64 * 65];
  const int bx = blockIdx.x;
  const int tid = threadIdx.x;
  if (bx < 2048) {
    const int k = bx * 16 + (tid >> 4);      // code index
    const int l16 = tid & 15;
    float s = 0.f;
#pragma unroll
    for (int v = 0; v < 4; v++) {
      const int off = (v * 16 + l16) * 4;    // k-offset, multiple of 4
      const float4 d = *(const float4*)(prior + (size_t)k * NF + off);
      uchar4 o;
      o.x = f2fp8(d.x * SP); o.y = f2fp8(d.y * SP);
      o.z = f2fp8(d.z * SP); o.w = f2fp8(d.w * SP);
      *(uchar4*)(p8 + (size_t)k * 256 + off) = o;          // natural order
      const float q0 = fp82f(o.x), q1 = fp82f(o.y), q2 = fp82f(o.z), q3 = fp82f(o.w);
      s += q0 * q0 + q1 * q1 + q2 * q2 + q3 * q3;
    }
#pragma unroll
    for (int mk = 8; mk >= 1; mk >>= 1) s += __shfl_xor(s, mk);
    if (l16 == 0) nbh[k] = 0.5f * s * (SX / SP);   // consistent scaled domain
  } else if (bx < 2112) {
    const int job = bx - 2048;
    const int l = job >> 4, t = job & 15;
    const int k0 = (t >> 3) * 64, n0 = (t & 7) * 64;
    const float* src = W1 + (size_t)l * NHALF * NHID;
#pragma unroll
    for (int v = 0; v < 16; v++) {
      const int e = tid + v * 256;
      const int kk = e >> 6, nn = e & 63;
      ts[kk * 65 + nn] = src[(size_t)(k0 + kk) * NHID + n0 + nn];
    }
    __syncthreads();
    unsigned short* dst = W1T + (size_t)l * NHID * NHALF;
#pragma unroll
    for (int v = 0; v < 16; v++) {
      const int e = tid + v * 256;
      const int nn = e >> 6, kk = e & 63;
      dst[(size_t)(n0 + nn) * NHALF + k0 + kk] = f2bf(ts[kk * 65 + nn]);
    }
  } else if (bx < 2240) {
    const int job = bx - 2112;
    const int l = job >> 5, rem = job & 31;
    const int b = rem >> 4;
    const int k0 = ((rem >> 1) & 7) * 64;
    const int f0 = (rem & 1) * 64;
    const float* src = (b ? Wt : Ws) + (size_t)l * NHID * NHALF;
#pragma unroll
    for (int v = 0; v < 16; v++) {
      const int e = tid + v * 256;
      const int kk = e >> 6, nn = e & 63;
      ts[kk * 65 + nn] = src[(size_t)(k0 + kk) * NHALF + f0 + nn];
    }
    __syncthreads();
#pragma unroll
    for (int v = 0; v < 16; v++) {
      const int e = tid + v * 256;
      const int nn = e >> 6, kk = e & 63;
      W2I[((size_t)l * NF + 2 * (f0 + nn) + b) * NHID + k0 + kk] = f2bf(ts[kk * 65 + nn]);
    }
  } else {
    const int idx = (bx - 2240) * 256 + tid;
    if (idx < NB) gbest[idx] = 0ull;
    if (idx < 4) accum[idx] = 0.f;    // [0]=dist [1]=jac [2]=ticket [3]=spare
  }
}

// ---------------------------------------------------------------- VQ finalize (+ fused loss)
// Last-arriving block (device-scope ticket on accum[2]) computes the scalar
// loss; accumulators read back via atomicAdd(p, 0) for cross-XCD coherence.
__global__ void vq_finalize(const float* __restrict__ X,      // d_out x, fp32
                            const float* __restrict__ prior,
                            const unsigned long long* __restrict__ gbest,
                            const float* __restrict__ jac,
                            float* __restrict__ accum,        // [0]=dist,[1]=jac,[2]=ticket
                            float* __restrict__ loss)
{
  const int wave = threadIdx.x >> 6, lane = threadIdx.x & 63;
  const int gw = blockIdx.x * 4 + wave;        // 1024 waves, 8 rows each
  float accd = 0.f, accj = 0.f;
  for (int r = 0; r < 8; r++) {
    const int row = gw * 8 + r;
    const unsigned int idx = ~(unsigned int)(gbest[row]);   // low 32 bits = ~idx
    const float* x = X + (size_t)row * NF;
    const float* p = prior + (size_t)idx * NF;
#pragma unroll
    for (int u = 0; u < 4; u++) {
      const int d = lane + u * 64;
      const float df = x[d] - p[d];
      accd += df * df;
    }
    if (lane == 0) accj += jac[row];
  }
#pragma unroll
  for (int mk = 32; mk >= 1; mk >>= 1) {
    accd += __shfl_xor(accd, mk);
    accj += __shfl_xor(accj, mk);
  }
  __shared__ float sd[4], sj[4];
  if (lane == 0) { sd[wave] = accd; sj[wave] = accj; }
  __syncthreads();
  if (threadIdx.x == 0) {
    atomicAdd(&accum[0], sd[0] + sd[1] + sd[2] + sd[3]);
    atomicAdd(&accum[1], sj[0] + sj[1] + sj[2] + sj[3]);
    __threadfence();                                        // release our adds
    const unsigned int t = atomicAdd((unsigned int*)&accum[2], 1u);
    if (t == 255u) {                                        // last of 256 blocks
      const float d = atomicAdd(&accum[0], 0.f);            // coherent read
      const float jv = atomicAdd(&accum[1], 0.f);
      loss[0] = 1.25f * (0.5f * d / (float)NB) - jv / (float)NB;
    }
  }
}

// ---------------------------------------------------------------- launch
extern "C" void kernel_launch(void* const* d_in, const int* in_sizes, int n_in,
                              void* d_out, int out_size, void* d_ws, size_t ws_size,
                              hipStream_t stream)
{
  (void)in_sizes; (void)n_in; (void)out_size; (void)ws_size;
  const float* inputs = (const float*)d_in[0];
  const float* W1 = (const float*)d_in[1];
  const float* b1 = (const float*)d_in[2];
  const float* Ws = (const float*)d_in[3];
  const float* bs = (const float*)d_in[4];
  const float* Wt = (const float*)d_in[5];
  const float* bt = (const float*)d_in[6];
  const float* prior = (const float*)d_in[7];

  char* p = (char*)d_ws;
  auto alloc = [&](size_t bytes) { char* r = p; p += (bytes + 255) & ~(size_t)255; return r; };
  unsigned short* W1T  = (unsigned short*)alloc((size_t)NLAY * NHID * NHALF * 2);
  unsigned short* W2I  = (unsigned short*)alloc((size_t)NLAY * NF * NHID * 2);
  unsigned char* P8    = (unsigned char*)alloc((size_t)NK * 256);
  float* NBH           = (float*)alloc((size_t)NK * 4);
  unsigned char* XF8   = (unsigned char*)alloc((size_t)NB * 256);
  float* JAC           = (float*)alloc((size_t)NB * 4);
  unsigned long long* GBEST = (unsigned long long*)alloc((size_t)NB * 8);
  float* ACC           = (float*)alloc(256);

  float* xout = (float*)d_out;                 // [NB][NF]
  float* loss = xout + (size_t)NB * NF;        // scalar

  prep_all<<<dim3(2272), 256, 0, stream>>>(
      W1, Ws, Wt, prior, W1T, W2I, P8, NBH, GBEST, ACC);

  flow_all<<<dim3(NB / 32), 512, 0, stream>>>(
      inputs, W1T, W2I, b1, bs, bt, xout, XF8, JAC);

  vq_argmax<<<dim3(32 * 16), 256, 0, stream>>>(XF8, P8, NBH, GBEST);
  vq_finalize<<<dim3(256), 256, 0, stream>>>(xout, prior, GBEST, JAC, ACC, loss);
}